// Round 7
// baseline (559.822 us; speedup 1.0000x reference)
//
#include <hip/hip_runtime.h>
#include <hip/hip_bf16.h>
#include <stdint.h>

#define D_MODEL 1024
#define N_HEADS 16
#define HEAD_DIM 64
#define B_SZ 4
#define T_SEQ 2048
#define BH_TOT (B_SZ * N_HEADS)     // 64
#define M_ROWS (B_SZ * T_SEQ)       // 8192
#define NROWS_TOT (BH_TOT * T_SEQ)  // 131072

typedef float floatx4 __attribute__((ext_vector_type(4)));
typedef __bf16 bf16x8 __attribute__((ext_vector_type(8)));

__device__ inline unsigned short f2bf(float f) {
  union { float f; unsigned int u; } c; c.f = f;
  unsigned int u = c.u;
  unsigned int r = (u + 0x7FFFu + ((u >> 16) & 1u)) >> 16;
  return (unsigned short)r;
}

__device__ inline unsigned short bfc(float f) {  // native cvt (RNE)
  return __builtin_bit_cast(unsigned short, (__bf16)f);
}

__device__ inline float bf2f(unsigned short u) {
  union { float f; unsigned int u; } c; c.u = ((unsigned int)u) << 16;
  return c.f;
}

__device__ __forceinline__ void gload16(const unsigned short* g,
                                        unsigned short* l) {
  __builtin_amdgcn_global_load_lds(
      (const __attribute__((address_space(1))) void*)g,
      (__attribute__((address_space(3))) void*)l, 16, 0, 0);
}

// ---------------- fp32 -> bf16 convert (no transpose) ----------------
__global__ void cvt_f32_bf16(const float* __restrict__ in,
                             unsigned short* __restrict__ out, int n) {
  int i = (blockIdx.x * blockDim.x + threadIdx.x) * 4;
  if (i + 3 < n) {
    float4 v = *(const float4*)(in + i);
    out[i + 0] = f2bf(v.x);
    out[i + 1] = f2bf(v.y);
    out[i + 2] = f2bf(v.z);
    out[i + 3] = f2bf(v.w);
  } else {
    for (; i < n; ++i) out[i] = f2bf(in[i]);
  }
}

// ---------------- fp32 [K][N] -> bf16 [N][K] transpose ----------------
__global__ __launch_bounds__(256) void cvt_transpose(
    const float* __restrict__ in, unsigned short* __restrict__ out,
    int K, int N) {
  __shared__ unsigned short tile[32][33];
  const int n0 = blockIdx.x * 32;
  const int k0 = blockIdx.y * 32;
  const int tx = threadIdx.x & 31;
  const int ty = threadIdx.x >> 5;  // 0..7
#pragma unroll
  for (int r = ty; r < 32; r += 8)
    tile[r][tx] = f2bf(in[(size_t)(k0 + r) * N + n0 + tx]);
  __syncthreads();
#pragma unroll
  for (int r = ty; r < 32; r += 8)
    out[(size_t)(n0 + r) * K + k0 + tx] = tile[tx][r];
}

// ---------------- bf16 V transpose: [bh][t][64] -> [bh][64][t] ----------
__global__ __launch_bounds__(256) void transpose_v(
    const unsigned short* __restrict__ Vb, unsigned short* __restrict__ Vt) {
  __shared__ unsigned short tile[32][33];
  const int t0 = blockIdx.x * 32;
  const int d0 = blockIdx.y * 32;
  const int bh = blockIdx.z;
  const unsigned short* src = Vb + (size_t)bh * T_SEQ * HEAD_DIM;
  unsigned short* dst = Vt + (size_t)bh * HEAD_DIM * T_SEQ;
  const int tx = threadIdx.x & 31;
  const int ty = threadIdx.x >> 5;
#pragma unroll
  for (int r = ty; r < 32; r += 8)
    tile[r][tx] = src[(size_t)(t0 + r) * HEAD_DIM + d0 + tx];
  __syncthreads();
#pragma unroll
  for (int r = ty; r < 32; r += 8)
    dst[(size_t)(d0 + r) * T_SEQ + t0 + tx] = tile[tx][r];
}

// ---------------- bf16 MFMA GEMM, 128x128 tile, BK=32, global_load_lds --
#define QSCALE 0.1803368801111204f  // 0.125 * log2(e)
template <int EPI>
__global__ __launch_bounds__(256) void gemm_bf16(
    const unsigned short* __restrict__ A,
    const unsigned short* __restrict__ Bt, int M, int N, int K,
    unsigned short* __restrict__ Qb, unsigned short* __restrict__ Kb,
    unsigned short* __restrict__ Vb, float* __restrict__ Cout) {
  const int bn = blockIdx.x * 128;
  const int bm = blockIdx.y * 128;
  const int tid = threadIdx.x;
  const int lane = tid & 63;
  const int w = tid >> 6;
  const int wr = w >> 1, wc = w & 1;  // 2x2 waves, each 64x64
  const int l15 = lane & 15;
  const int lg = lane >> 4;

  __shared__ unsigned short As[128 * 32];
  __shared__ unsigned short Bs[128 * 32];

  floatx4 acc[4][4] = {};

  const int srow = w * 16 + (lane >> 2);  // staging row (0..63)
  const int scol = (lane & 3) * 8;

  for (int k0 = 0; k0 < K; k0 += 32) {
    gload16(&A[(size_t)(bm + srow) * K + k0 + scol], &As[w * 512]);
    gload16(&A[(size_t)(bm + 64 + srow) * K + k0 + scol], &As[2048 + w * 512]);
    gload16(&Bt[(size_t)(bn + srow) * K + k0 + scol], &Bs[w * 512]);
    gload16(&Bt[(size_t)(bn + 64 + srow) * K + k0 + scol], &Bs[2048 + w * 512]);

    __syncthreads();

    bf16x8 af[4], bfr[4];
#pragma unroll
    for (int mt = 0; mt < 4; ++mt)
      af[mt] = *(const bf16x8*)&As[(wr * 64 + mt * 16 + l15) * 32 + lg * 8];
#pragma unroll
    for (int nt = 0; nt < 4; ++nt)
      bfr[nt] = *(const bf16x8*)&Bs[(wc * 64 + nt * 16 + l15) * 32 + lg * 8];
#pragma unroll
    for (int mt = 0; mt < 4; ++mt)
#pragma unroll
      for (int nt = 0; nt < 4; ++nt)
        acc[mt][nt] = __builtin_amdgcn_mfma_f32_16x16x32_bf16(
            af[mt], bfr[nt], acc[mt][nt], 0, 0, 0);

    __syncthreads();
  }

#pragma unroll
  for (int mt = 0; mt < 4; ++mt)
#pragma unroll
    for (int nt = 0; nt < 4; ++nt)
#pragma unroll
      for (int i = 0; i < 4; ++i) {
        int m = bm + wr * 64 + mt * 16 + lg * 4 + i;
        int n = bn + wc * 64 + nt * 16 + l15;
        float v = acc[mt][nt][i];
        if (EPI == 0) {
          int b = m >> 11;
          int t = m & (T_SEQ - 1);
          int part = n >> 10;  // 0=q 1=k 2=v
          int nn = n & (D_MODEL - 1);
          int h = nn >> 6;
          int dh = nn & 63;
          size_t idx = ((size_t)(b * N_HEADS + h) * T_SEQ + t) * HEAD_DIM + dh;
          if (part == 0)
            Qb[idx] = bfc(v * QSCALE);
          else if (part == 1)
            Kb[idx] = bfc(v);
          else
            Vb[idx] = bfc(v);
        } else {
          Cout[(size_t)m * N + n] = v;
        }
      }
}

// ---------------- causal flash attention, balanced pairs + KV-split -----
// Block (head, p, s): two q-tiles (rows [128p,128p+128) and mirror), each
// phase's KV steps split in half across s. 17 steps/block, uniform.
// r5-proven 2-barrier pipeline + r6-proven LDS slot-XOR swizzle.
// Writes UNNORMALIZED partials (o bf16, m/l fp32); merged by attn_merge.
__global__ __launch_bounds__(256, 4) void attn_fwd(
    const unsigned short* __restrict__ Qb, const unsigned short* __restrict__ Kb,
    const unsigned short* __restrict__ Vt, unsigned short* __restrict__ Po0,
    unsigned short* __restrict__ Po1, float* __restrict__ Pm,
    float* __restrict__ Pl) {
  const int head = blockIdx.x;  // 0..63
  const int p = blockIdx.y;     // 0..7
  const int s = blockIdx.z;     // 0..1
  const int tid = threadIdx.x;
  const int wid = tid >> 6;
  const int lane = tid & 63;
  const int l15 = lane & 15;
  const int lg = lane >> 4;
  const int l7 = l15 & 7;

  const unsigned short* Qh = Qb + (size_t)head * T_SEQ * HEAD_DIM;
  const unsigned short* Kh = Kb + (size_t)head * T_SEQ * HEAD_DIM;
  const unsigned short* Vh = Vt + (size_t)head * HEAD_DIM * T_SEQ;
  unsigned short* Po = s ? Po1 : Po0;

  __shared__ unsigned short Ks[64 * 64];
  __shared__ unsigned short Vs[64 * 64];
  __shared__ unsigned short Plds[4][2][16 * 64];

  // staging map: thread -> row (0..63), two swizzled 16B slots
  const int st_row = tid >> 2;
  const int st_s0 = (tid & 3) * 2;
  const int st_r7 = st_row & 7;
  const int wAddr0 = st_row * 64 + ((st_s0 ^ st_r7) << 3);
  const int wAddr1 = st_row * 64 + (((st_s0 + 1) ^ st_r7) << 3);
  const int gcol = (tid & 3) * 16;

  for (int ph = 0; ph < 2; ++ph) {
    const int rbase = (ph == 0) ? p * 128 : 2048 - 128 * (p + 1);
    const int nst = (ph == 0) ? 2 * p + 2 : 32 - 2 * p;  // even
    const int half = nst >> 1;
    const int kb0 = s * half, kb1 = kb0 + half;
    const int q0 = rbase + wid * 32;

    bf16x8 qf[2][2];
#pragma unroll
    for (int t = 0; t < 2; ++t)
#pragma unroll
      for (int c = 0; c < 2; ++c)
        qf[t][c] = *(const bf16x8*)&Qh[(size_t)(q0 + t * 16 + l15) * 64 +
                                       c * 32 + lg * 8];

    floatx4 o[2][4] = {};
    float m_run[2][4], l_part[2][4];
#pragma unroll
    for (int t = 0; t < 2; ++t)
#pragma unroll
      for (int i = 0; i < 4; ++i) {
        m_run[t][i] = -3000.0f;  // finite: fully-masked rows -> exact 0
        l_part[t][i] = 0.f;
      }

    // prologue: load first chunk into regs
    uint4 ka, kb2, va, vb2;
    {
      const int nb = kb0 * 64;
      const uint4* gk = (const uint4*)&Kh[(size_t)(nb + st_row) * 64 + gcol];
      ka = gk[0]; kb2 = gk[1];
      const uint4* gv = (const uint4*)&Vh[(size_t)st_row * T_SEQ + nb + gcol];
      va = gv[0]; vb2 = gv[1];
    }

    for (int kb = kb0; kb < kb1; ++kb) {
      const int kbase = kb * 64;
      // write staged regs -> LDS (swizzled)
      *(uint4*)&Ks[wAddr0] = ka;
      *(uint4*)&Ks[wAddr1] = kb2;
      *(uint4*)&Vs[wAddr0] = va;
      *(uint4*)&Vs[wAddr1] = vb2;
      if (kb + 1 < kb1) {  // prefetch next chunk (hides under compute)
        const int nb = kbase + 64;
        const uint4* gk = (const uint4*)&Kh[(size_t)(nb + st_row) * 64 + gcol];
        ka = gk[0]; kb2 = gk[1];
        const uint4* gv = (const uint4*)&Vh[(size_t)st_row * T_SEQ + nb + gcol];
        va = gv[0]; vb2 = gv[1];
      }
      __syncthreads();

      if (kbase <= q0 + 31) {  // causal work remains for this wave
        bf16x8 kf0[4], kf1[4];
#pragma unroll
        for (int c = 0; c < 4; ++c) {
          kf0[c] = *(const bf16x8*)&Ks[(c * 16 + l15) * 64 + ((lg ^ l7) << 3)];
          kf1[c] =
              *(const bf16x8*)&Ks[(c * 16 + l15) * 64 + (((4 + lg) ^ l7) << 3)];
        }
        bf16x8 vf[2][4];
#pragma unroll
        for (int kc = 0; kc < 2; ++kc)
#pragma unroll
          for (int d = 0; d < 4; ++d)
            vf[kc][d] = *(const bf16x8*)&Vs[(d * 16 + l15) * 64 +
                                            (((kc * 4 + lg) ^ l7) << 3)];

        floatx4 sc[2][4] = {};
        __builtin_amdgcn_s_setprio(1);
#pragma unroll
        for (int c = 0; c < 4; ++c) {
          sc[0][c] = __builtin_amdgcn_mfma_f32_16x16x32_bf16(qf[0][0], kf0[c], sc[0][c], 0, 0, 0);
          sc[0][c] = __builtin_amdgcn_mfma_f32_16x16x32_bf16(qf[0][1], kf1[c], sc[0][c], 0, 0, 0);
          sc[1][c] = __builtin_amdgcn_mfma_f32_16x16x32_bf16(qf[1][0], kf0[c], sc[1][c], 0, 0, 0);
          sc[1][c] = __builtin_amdgcn_mfma_f32_16x16x32_bf16(qf[1][1], kf1[c], sc[1][c], 0, 0, 0);
        }
        __builtin_amdgcn_s_setprio(0);

        const int kq = kbase - q0;
        const bool needmask = (kbase + 63 > q0);
#pragma unroll
        for (int t = 0; t < 2; ++t) {
          if (needmask) {
#pragma unroll
            for (int i = 0; i < 4; ++i) {
              int qoff = t * 16 + lg * 4 + i;
#pragma unroll
              for (int c = 0; c < 4; ++c)
                if (c * 16 + l15 + kq > qoff) sc[t][c][i] = -1e30f;
            }
          }

          float lmax[4];
          bool need = false;
#pragma unroll
          for (int i = 0; i < 4; ++i) {
            lmax[i] = fmaxf(fmaxf(sc[t][0][i], sc[t][1][i]),
                            fmaxf(sc[t][2][i], sc[t][3][i]));
            need |= (lmax[i] > m_run[t][i] + 8.0f);
          }
          if (__any(need)) {
#pragma unroll
            for (int i = 0; i < 4; ++i) {
              float pm = lmax[i];
              pm = fmaxf(pm, __shfl_xor(pm, 1));
              pm = fmaxf(pm, __shfl_xor(pm, 2));
              pm = fmaxf(pm, __shfl_xor(pm, 4));
              pm = fmaxf(pm, __shfl_xor(pm, 8));
              float mnew = fmaxf(m_run[t][i], pm);
              float alpha = exp2f(m_run[t][i] - mnew);
              m_run[t][i] = mnew;
              l_part[t][i] *= alpha;
              o[t][0][i] *= alpha;
              o[t][1][i] *= alpha;
              o[t][2][i] *= alpha;
              o[t][3][i] *= alpha;
            }
          }
          unsigned short* Pw = Plds[wid][t];
#pragma unroll
          for (int i = 0; i < 4; ++i) {
#pragma unroll
            for (int c = 0; c < 4; ++c)
              sc[t][c][i] = exp2f(sc[t][c][i] - m_run[t][i]);
            l_part[t][i] += (sc[t][0][i] + sc[t][1][i]) + (sc[t][2][i] + sc[t][3][i]);
            const int prow = lg * 4 + i;
#pragma unroll
            for (int c = 0; c < 4; ++c) {
              int slot = c * 2 + (l15 >> 3);
              Pw[prow * 64 + (((slot ^ (prow & 7)) << 3) + l7)] =
                  bfc(sc[t][c][i]);
            }
          }
        }

        __builtin_amdgcn_s_setprio(1);
#pragma unroll
        for (int t = 0; t < 2; ++t) {
          const unsigned short* Pr = Plds[wid][t];
          bf16x8 pf0 = *(const bf16x8*)&Pr[l15 * 64 + ((lg ^ l7) << 3)];
          bf16x8 pf1 = *(const bf16x8*)&Pr[l15 * 64 + (((4 + lg) ^ l7) << 3)];
#pragma unroll
          for (int d = 0; d < 4; ++d) {
            o[t][d] = __builtin_amdgcn_mfma_f32_16x16x32_bf16(pf0, vf[0][d], o[t][d], 0, 0, 0);
            o[t][d] = __builtin_amdgcn_mfma_f32_16x16x32_bf16(pf1, vf[1][d], o[t][d], 0, 0, 0);
          }
        }
        __builtin_amdgcn_s_setprio(0);
      }

      __syncthreads();
    }

    // epilogue: reduce lane-partial l, write unnormalized partials
#pragma unroll
    for (int t = 0; t < 2; ++t)
#pragma unroll
      for (int i = 0; i < 4; ++i) {
        float l = l_part[t][i];
        l += __shfl_xor(l, 1);
        l += __shfl_xor(l, 2);
        l += __shfl_xor(l, 4);
        l += __shfl_xor(l, 8);
        int r = q0 + t * 16 + lg * 4 + i;
        size_t rw = (size_t)head * T_SEQ + r;
        if (l15 == 0) {
          Pm[(size_t)s * NROWS_TOT + rw] = m_run[t][i];
          Pl[(size_t)s * NROWS_TOT + rw] = l;
        }
#pragma unroll
        for (int d = 0; d < 4; ++d)
          Po[rw * 64 + d * 16 + l15] = bfc(o[t][d][i]);
      }
  }
}

// ---------------- merge the two KV-split partials ----------------
__global__ __launch_bounds__(256) void attn_merge(
    const unsigned short* __restrict__ Po0,
    const unsigned short* __restrict__ Po1, const float* __restrict__ Pm,
    const float* __restrict__ Pl, unsigned short* __restrict__ Ob) {
  int idx = blockIdx.x * 256 + threadIdx.x;  // one 4-col chunk
  int row = idx >> 4;                        // head*2048 + r
  int dc = (idx & 15) * 4;
  float m0 = Pm[row], m1 = Pm[NROWS_TOT + row];
  float l0 = Pl[row], l1 = Pl[NROWS_TOT + row];
  float M = fmaxf(m0, m1);
  float w0 = exp2f(m0 - M), w1 = exp2f(m1 - M);
  float inv = 1.0f / (w0 * l0 + w1 * l1);
  w0 *= inv;
  w1 *= inv;
  ushort4 a = *(const ushort4*)&Po0[(size_t)row * 64 + dc];
  ushort4 b4 = *(const ushort4*)&Po1[(size_t)row * 64 + dc];
  int head = row >> 11;
  int r = row & 2047;
  int bb = head >> 4, hh = head & 15;
  size_t base = ((size_t)(bb * T_SEQ + r)) * D_MODEL + hh * HEAD_DIM + dc;
  Ob[base + 0] = bfc(w0 * bf2f(a.x) + w1 * bf2f(b4.x));
  Ob[base + 1] = bfc(w0 * bf2f(a.y) + w1 * bf2f(b4.y));
  Ob[base + 2] = bfc(w0 * bf2f(a.z) + w1 * bf2f(b4.z));
  Ob[base + 3] = bfc(w0 * bf2f(a.w) + w1 * bf2f(b4.w));
}

extern "C" void kernel_launch(void* const* d_in, const int* in_sizes, int n_in,
                              void* d_out, int out_size, void* d_ws,
                              size_t ws_size, hipStream_t stream) {
  const float* x = (const float*)d_in[0];
  const float* w_qkv = (const float*)d_in[1];
  const float* w_proj = (const float*)d_in[2];
  float* out = (float*)d_out;

  char* ws = (char*)d_ws;
  size_t off = 0;
  unsigned short* x_bf = (unsigned short*)(ws + off);
  off += (size_t)M_ROWS * D_MODEL * 2;
  unsigned short* wqkv_t = (unsigned short*)(ws + off);
  off += (size_t)D_MODEL * 3 * D_MODEL * 2;
  unsigned short* wproj_t = (unsigned short*)(ws + off);
  off += (size_t)D_MODEL * D_MODEL * 2;
  unsigned short* Qb = (unsigned short*)(ws + off);
  off += (size_t)BH_TOT * T_SEQ * HEAD_DIM * 2;
  unsigned short* Kb = (unsigned short*)(ws + off);
  off += (size_t)BH_TOT * T_SEQ * HEAD_DIM * 2;
  unsigned short* Vb = (unsigned short*)(ws + off);
  off += (size_t)BH_TOT * T_SEQ * HEAD_DIM * 2;
  unsigned short* Vt = (unsigned short*)(ws + off);
  off += (size_t)BH_TOT * T_SEQ * HEAD_DIM * 2;
  unsigned short* Ob = (unsigned short*)(ws + off);
  off += (size_t)M_ROWS * D_MODEL * 2;

  // partial buffers reuse regions dead after the qkv GEMM / transpose_v:
  unsigned short* Po0 = x_bf;              // 16.8 MB, free after gemm<0>
  unsigned short* Po1 = Vb;                // 16.8 MB, free after transpose_v
  float* Pm = (float*)wqkv_t;              // 1.05 MB  (wqkv_t free after gemm<0>)
  float* Pl = Pm + 2 * NROWS_TOT;          // 1.05 MB

  int n1 = M_ROWS * D_MODEL;
  cvt_f32_bf16<<<(n1 / 4 + 255) / 256, 256, 0, stream>>>(x, x_bf, n1);
  cvt_transpose<<<dim3(3 * D_MODEL / 32, D_MODEL / 32), 256, 0, stream>>>(
      w_qkv, wqkv_t, D_MODEL, 3 * D_MODEL);
  cvt_transpose<<<dim3(D_MODEL / 32, D_MODEL / 32), 256, 0, stream>>>(
      w_proj, wproj_t, D_MODEL, D_MODEL);

  gemm_bf16<0><<<dim3(3 * D_MODEL / 128, M_ROWS / 128), 256, 0, stream>>>(
      x_bf, wqkv_t, M_ROWS, 3 * D_MODEL, D_MODEL, Qb, Kb, Vb, nullptr);

  transpose_v<<<dim3(T_SEQ / 32, HEAD_DIM / 32, BH_TOT), 256, 0, stream>>>(Vb, Vt);

  attn_fwd<<<dim3(BH_TOT, 8, 2), 256, 0, stream>>>(Qb, Kb, Vt, Po0, Po1, Pm, Pl);

  attn_merge<<<(NROWS_TOT * 16) / 256, 256, 0, stream>>>(Po0, Po1, Pm, Pl, Ob);

  gemm_bf16<1><<<dim3(D_MODEL / 128, M_ROWS / 128), 256, 0, stream>>>(
      Ob, wproj_t, M_ROWS, D_MODEL, D_MODEL, nullptr, nullptr, nullptr, out);
}

// Round 8
// 291.631 us; speedup vs baseline: 1.9196x; 1.9196x over previous
//
#include <hip/hip_runtime.h>
#include <hip/hip_bf16.h>
#include <stdint.h>

#define D_MODEL 1024
#define N_HEADS 16
#define HEAD_DIM 64
#define B_SZ 4
#define T_SEQ 2048
#define BH_TOT (B_SZ * N_HEADS)     // 64
#define M_ROWS (B_SZ * T_SEQ)       // 8192
#define NROWS_TOT (BH_TOT * T_SEQ)  // 131072

typedef float floatx4 __attribute__((ext_vector_type(4)));
typedef __bf16 bf16x8 __attribute__((ext_vector_type(8)));

__device__ inline unsigned short f2bf(float f) {
  union { float f; unsigned int u; } c; c.f = f;
  unsigned int u = c.u;
  unsigned int r = (u + 0x7FFFu + ((u >> 16) & 1u)) >> 16;
  return (unsigned short)r;
}

__device__ inline unsigned short bfc(float f) {  // native cvt (RNE)
  return __builtin_bit_cast(unsigned short, (__bf16)f);
}

__device__ inline float bf2f(unsigned short u) {
  union { float f; unsigned int u; } c; c.u = ((unsigned int)u) << 16;
  return c.f;
}

__device__ __forceinline__ void gload16(const unsigned short* g,
                                        unsigned short* l) {
  __builtin_amdgcn_global_load_lds(
      (const __attribute__((address_space(1))) void*)g,
      (__attribute__((address_space(3))) void*)l, 16, 0, 0);
}

// ---------------- fp32 -> bf16 convert (no transpose) ----------------
__global__ void cvt_f32_bf16(const float* __restrict__ in,
                             unsigned short* __restrict__ out, int n) {
  int i = (blockIdx.x * blockDim.x + threadIdx.x) * 4;
  if (i + 3 < n) {
    float4 v = *(const float4*)(in + i);
    out[i + 0] = f2bf(v.x);
    out[i + 1] = f2bf(v.y);
    out[i + 2] = f2bf(v.z);
    out[i + 3] = f2bf(v.w);
  } else {
    for (; i < n; ++i) out[i] = f2bf(in[i]);
  }
}

// ---------------- fp32 [K][N] -> bf16 [N][K] transpose ----------------
__global__ __launch_bounds__(256) void cvt_transpose(
    const float* __restrict__ in, unsigned short* __restrict__ out,
    int K, int N) {
  __shared__ unsigned short tile[32][33];
  const int n0 = blockIdx.x * 32;
  const int k0 = blockIdx.y * 32;
  const int tx = threadIdx.x & 31;
  const int ty = threadIdx.x >> 5;  // 0..7
#pragma unroll
  for (int r = ty; r < 32; r += 8)
    tile[r][tx] = f2bf(in[(size_t)(k0 + r) * N + n0 + tx]);
  __syncthreads();
#pragma unroll
  for (int r = ty; r < 32; r += 8)
    out[(size_t)(n0 + r) * K + k0 + tx] = tile[tx][r];
}

// ---------------- bf16 V transpose: [bh][t][64] -> [bh][64][t] ----------
__global__ __launch_bounds__(256) void transpose_v(
    const unsigned short* __restrict__ Vb, unsigned short* __restrict__ Vt) {
  __shared__ unsigned short tile[32][33];
  const int t0 = blockIdx.x * 32;
  const int d0 = blockIdx.y * 32;
  const int bh = blockIdx.z;
  const unsigned short* src = Vb + (size_t)bh * T_SEQ * HEAD_DIM;
  unsigned short* dst = Vt + (size_t)bh * HEAD_DIM * T_SEQ;
  const int tx = threadIdx.x & 31;
  const int ty = threadIdx.x >> 5;
#pragma unroll
  for (int r = ty; r < 32; r += 8)
    tile[r][tx] = src[(size_t)(t0 + r) * HEAD_DIM + d0 + tx];
  __syncthreads();
#pragma unroll
  for (int r = ty; r < 32; r += 8)
    dst[(size_t)(d0 + r) * T_SEQ + t0 + tx] = tile[tx][r];
}

// ---------------- bf16 MFMA GEMM, 128x128 tile, BK=32, global_load_lds --
#define QSCALE 0.1803368801111204f  // 0.125 * log2(e)
template <int EPI>
__global__ __launch_bounds__(256) void gemm_bf16(
    const unsigned short* __restrict__ A,
    const unsigned short* __restrict__ Bt, int M, int N, int K,
    unsigned short* __restrict__ Qb, unsigned short* __restrict__ Kb,
    unsigned short* __restrict__ Vb, float* __restrict__ Cout) {
  const int bn = blockIdx.x * 128;
  const int bm = blockIdx.y * 128;
  const int tid = threadIdx.x;
  const int lane = tid & 63;
  const int w = tid >> 6;
  const int wr = w >> 1, wc = w & 1;  // 2x2 waves, each 64x64
  const int l15 = lane & 15;
  const int lg = lane >> 4;

  __shared__ unsigned short As[128 * 32];
  __shared__ unsigned short Bs[128 * 32];

  floatx4 acc[4][4] = {};

  const int srow = w * 16 + (lane >> 2);  // staging row (0..63)
  const int scol = (lane & 3) * 8;

  for (int k0 = 0; k0 < K; k0 += 32) {
    gload16(&A[(size_t)(bm + srow) * K + k0 + scol], &As[w * 512]);
    gload16(&A[(size_t)(bm + 64 + srow) * K + k0 + scol], &As[2048 + w * 512]);
    gload16(&Bt[(size_t)(bn + srow) * K + k0 + scol], &Bs[w * 512]);
    gload16(&Bt[(size_t)(bn + 64 + srow) * K + k0 + scol], &Bs[2048 + w * 512]);

    __syncthreads();

    bf16x8 af[4], bfr[4];
#pragma unroll
    for (int mt = 0; mt < 4; ++mt)
      af[mt] = *(const bf16x8*)&As[(wr * 64 + mt * 16 + l15) * 32 + lg * 8];
#pragma unroll
    for (int nt = 0; nt < 4; ++nt)
      bfr[nt] = *(const bf16x8*)&Bs[(wc * 64 + nt * 16 + l15) * 32 + lg * 8];
#pragma unroll
    for (int mt = 0; mt < 4; ++mt)
#pragma unroll
      for (int nt = 0; nt < 4; ++nt)
        acc[mt][nt] = __builtin_amdgcn_mfma_f32_16x16x32_bf16(
            af[mt], bfr[nt], acc[mt][nt], 0, 0, 0);

    __syncthreads();
  }

#pragma unroll
  for (int mt = 0; mt < 4; ++mt)
#pragma unroll
    for (int nt = 0; nt < 4; ++nt)
#pragma unroll
      for (int i = 0; i < 4; ++i) {
        int m = bm + wr * 64 + mt * 16 + lg * 4 + i;
        int n = bn + wc * 64 + nt * 16 + l15;
        float v = acc[mt][nt][i];
        if (EPI == 0) {
          int b = m >> 11;
          int t = m & (T_SEQ - 1);
          int part = n >> 10;  // 0=q 1=k 2=v
          int nn = n & (D_MODEL - 1);
          int h = nn >> 6;
          int dh = nn & 63;
          size_t idx = ((size_t)(b * N_HEADS + h) * T_SEQ + t) * HEAD_DIM + dh;
          if (part == 0)
            Qb[idx] = bfc(v * QSCALE);
          else if (part == 1)
            Kb[idx] = bfc(v);
          else
            Vb[idx] = bfc(v);
        } else {
          Cout[(size_t)m * N + n] = v;
        }
      }
}

// ---------------- causal flash attention, balanced pairs + KV-split -----
// Block (head, p, s): two q-tiles (rows [128p,128p+128) and mirror), each
// phase's KV steps split in half across s. 17 steps/block, uniform.
// r5-proven 2-barrier pipeline + r6-proven LDS slot-XOR swizzle.
// NOTE: plain __launch_bounds__(256) — (256,4) in r7 forced VGPR=64 and
// 1 GB of scratch spill traffic (418 us). Let the allocator breathe.
__global__ __launch_bounds__(256) void attn_fwd(
    const unsigned short* __restrict__ Qb, const unsigned short* __restrict__ Kb,
    const unsigned short* __restrict__ Vt, unsigned short* __restrict__ Po0,
    unsigned short* __restrict__ Po1, float* __restrict__ Pm,
    float* __restrict__ Pl) {
  const int head = blockIdx.x;  // 0..63
  const int p = blockIdx.y;     // 0..7
  const int s = blockIdx.z;     // 0..1
  const int tid = threadIdx.x;
  const int wid = tid >> 6;
  const int lane = tid & 63;
  const int l15 = lane & 15;
  const int lg = lane >> 4;
  const int l7 = l15 & 7;

  const unsigned short* Qh = Qb + (size_t)head * T_SEQ * HEAD_DIM;
  const unsigned short* Kh = Kb + (size_t)head * T_SEQ * HEAD_DIM;
  const unsigned short* Vh = Vt + (size_t)head * HEAD_DIM * T_SEQ;
  unsigned short* Po = s ? Po1 : Po0;

  __shared__ unsigned short Ks[64 * 64];
  __shared__ unsigned short Vs[64 * 64];
  __shared__ unsigned short Plds[4][2][16 * 64];

  // staging map: thread -> row (0..63), two swizzled 16B slots
  const int st_row = tid >> 2;
  const int st_s0 = (tid & 3) * 2;
  const int st_r7 = st_row & 7;
  const int wAddr0 = st_row * 64 + ((st_s0 ^ st_r7) << 3);
  const int wAddr1 = st_row * 64 + (((st_s0 + 1) ^ st_r7) << 3);
  const int gcol = (tid & 3) * 16;

  for (int ph = 0; ph < 2; ++ph) {
    const int rbase = (ph == 0) ? p * 128 : 2048 - 128 * (p + 1);
    const int nst = (ph == 0) ? 2 * p + 2 : 32 - 2 * p;  // even
    const int half = nst >> 1;
    const int kb0 = s * half, kb1 = kb0 + half;
    const int q0 = rbase + wid * 32;

    bf16x8 qf[2][2];
#pragma unroll
    for (int t = 0; t < 2; ++t)
#pragma unroll
      for (int c = 0; c < 2; ++c)
        qf[t][c] = *(const bf16x8*)&Qh[(size_t)(q0 + t * 16 + l15) * 64 +
                                       c * 32 + lg * 8];

    floatx4 o[2][4] = {};
    float m_run[2][4], l_part[2][4];
#pragma unroll
    for (int t = 0; t < 2; ++t)
#pragma unroll
      for (int i = 0; i < 4; ++i) {
        m_run[t][i] = -3000.0f;  // finite: fully-masked rows -> exact 0
        l_part[t][i] = 0.f;
      }

    // prologue: load first chunk into regs
    uint4 ka, kb2, va, vb2;
    {
      const int nb = kb0 * 64;
      const uint4* gk = (const uint4*)&Kh[(size_t)(nb + st_row) * 64 + gcol];
      ka = gk[0]; kb2 = gk[1];
      const uint4* gv = (const uint4*)&Vh[(size_t)st_row * T_SEQ + nb + gcol];
      va = gv[0]; vb2 = gv[1];
    }

    for (int kb = kb0; kb < kb1; ++kb) {
      const int kbase = kb * 64;
      // write staged regs -> LDS (swizzled)
      *(uint4*)&Ks[wAddr0] = ka;
      *(uint4*)&Ks[wAddr1] = kb2;
      *(uint4*)&Vs[wAddr0] = va;
      *(uint4*)&Vs[wAddr1] = vb2;
      if (kb + 1 < kb1) {  // prefetch next chunk (hides under compute)
        const int nb = kbase + 64;
        const uint4* gk = (const uint4*)&Kh[(size_t)(nb + st_row) * 64 + gcol];
        ka = gk[0]; kb2 = gk[1];
        const uint4* gv = (const uint4*)&Vh[(size_t)st_row * T_SEQ + nb + gcol];
        va = gv[0]; vb2 = gv[1];
      }
      __syncthreads();

      if (kbase <= q0 + 31) {  // causal work remains for this wave
        bf16x8 kf0[4], kf1[4];
#pragma unroll
        for (int c = 0; c < 4; ++c) {
          kf0[c] = *(const bf16x8*)&Ks[(c * 16 + l15) * 64 + ((lg ^ l7) << 3)];
          kf1[c] =
              *(const bf16x8*)&Ks[(c * 16 + l15) * 64 + (((4 + lg) ^ l7) << 3)];
        }
        bf16x8 vf[2][4];
#pragma unroll
        for (int kc = 0; kc < 2; ++kc)
#pragma unroll
          for (int d = 0; d < 4; ++d)
            vf[kc][d] = *(const bf16x8*)&Vs[(d * 16 + l15) * 64 +
                                            (((kc * 4 + lg) ^ l7) << 3)];

        floatx4 sc[2][4] = {};
        __builtin_amdgcn_s_setprio(1);
#pragma unroll
        for (int c = 0; c < 4; ++c) {
          sc[0][c] = __builtin_amdgcn_mfma_f32_16x16x32_bf16(qf[0][0], kf0[c], sc[0][c], 0, 0, 0);
          sc[0][c] = __builtin_amdgcn_mfma_f32_16x16x32_bf16(qf[0][1], kf1[c], sc[0][c], 0, 0, 0);
          sc[1][c] = __builtin_amdgcn_mfma_f32_16x16x32_bf16(qf[1][0], kf0[c], sc[1][c], 0, 0, 0);
          sc[1][c] = __builtin_amdgcn_mfma_f32_16x16x32_bf16(qf[1][1], kf1[c], sc[1][c], 0, 0, 0);
        }
        __builtin_amdgcn_s_setprio(0);

        const int kq = kbase - q0;
        const bool needmask = (kbase + 63 > q0);
#pragma unroll
        for (int t = 0; t < 2; ++t) {
          if (needmask) {
#pragma unroll
            for (int i = 0; i < 4; ++i) {
              int qoff = t * 16 + lg * 4 + i;
#pragma unroll
              for (int c = 0; c < 4; ++c)
                if (c * 16 + l15 + kq > qoff) sc[t][c][i] = -1e30f;
            }
          }

          float lmax[4];
          bool need = false;
#pragma unroll
          for (int i = 0; i < 4; ++i) {
            lmax[i] = fmaxf(fmaxf(sc[t][0][i], sc[t][1][i]),
                            fmaxf(sc[t][2][i], sc[t][3][i]));
            need |= (lmax[i] > m_run[t][i] + 8.0f);
          }
          if (__any(need)) {
#pragma unroll
            for (int i = 0; i < 4; ++i) {
              float pm = lmax[i];
              pm = fmaxf(pm, __shfl_xor(pm, 1));
              pm = fmaxf(pm, __shfl_xor(pm, 2));
              pm = fmaxf(pm, __shfl_xor(pm, 4));
              pm = fmaxf(pm, __shfl_xor(pm, 8));
              float mnew = fmaxf(m_run[t][i], pm);
              float alpha = exp2f(m_run[t][i] - mnew);
              m_run[t][i] = mnew;
              l_part[t][i] *= alpha;
              o[t][0][i] *= alpha;
              o[t][1][i] *= alpha;
              o[t][2][i] *= alpha;
              o[t][3][i] *= alpha;
            }
          }
          unsigned short* Pw = Plds[wid][t];
#pragma unroll
          for (int i = 0; i < 4; ++i) {
#pragma unroll
            for (int c = 0; c < 4; ++c)
              sc[t][c][i] = exp2f(sc[t][c][i] - m_run[t][i]);
            l_part[t][i] += (sc[t][0][i] + sc[t][1][i]) + (sc[t][2][i] + sc[t][3][i]);
            const int prow = lg * 4 + i;
#pragma unroll
            for (int c = 0; c < 4; ++c) {
              int slot = c * 2 + (l15 >> 3);
              Pw[prow * 64 + (((slot ^ (prow & 7)) << 3) + l7)] =
                  bfc(sc[t][c][i]);
            }
          }
        }

        __builtin_amdgcn_s_setprio(1);
#pragma unroll
        for (int t = 0; t < 2; ++t) {
          const unsigned short* Pr = Plds[wid][t];
          bf16x8 pf0 = *(const bf16x8*)&Pr[l15 * 64 + ((lg ^ l7) << 3)];
          bf16x8 pf1 = *(const bf16x8*)&Pr[l15 * 64 + (((4 + lg) ^ l7) << 3)];
#pragma unroll
          for (int d = 0; d < 4; ++d) {
            o[t][d] = __builtin_amdgcn_mfma_f32_16x16x32_bf16(pf0, vf[0][d], o[t][d], 0, 0, 0);
            o[t][d] = __builtin_amdgcn_mfma_f32_16x16x32_bf16(pf1, vf[1][d], o[t][d], 0, 0, 0);
          }
        }
        __builtin_amdgcn_s_setprio(0);
      }

      __syncthreads();
    }

    // epilogue: reduce lane-partial l, write unnormalized partials
#pragma unroll
    for (int t = 0; t < 2; ++t)
#pragma unroll
      for (int i = 0; i < 4; ++i) {
        float l = l_part[t][i];
        l += __shfl_xor(l, 1);
        l += __shfl_xor(l, 2);
        l += __shfl_xor(l, 4);
        l += __shfl_xor(l, 8);
        int r = q0 + t * 16 + lg * 4 + i;
        size_t rw = (size_t)head * T_SEQ + r;
        if (l15 == 0) {
          Pm[(size_t)s * NROWS_TOT + rw] = m_run[t][i];
          Pl[(size_t)s * NROWS_TOT + rw] = l;
        }
#pragma unroll
        for (int d = 0; d < 4; ++d)
          Po[rw * 64 + d * 16 + l15] = bfc(o[t][d][i]);
      }
  }
}

// ---------------- merge the two KV-split partials ----------------
__global__ __launch_bounds__(256) void attn_merge(
    const unsigned short* __restrict__ Po0,
    const unsigned short* __restrict__ Po1, const float* __restrict__ Pm,
    const float* __restrict__ Pl, unsigned short* __restrict__ Ob) {
  int idx = blockIdx.x * 256 + threadIdx.x;  // one 4-col chunk
  int row = idx >> 4;                        // head*2048 + r
  int dc = (idx & 15) * 4;
  float m0 = Pm[row], m1 = Pm[NROWS_TOT + row];
  float l0 = Pl[row], l1 = Pl[NROWS_TOT + row];
  float M = fmaxf(m0, m1);
  float w0 = exp2f(m0 - M), w1 = exp2f(m1 - M);
  float inv = 1.0f / (w0 * l0 + w1 * l1);
  w0 *= inv;
  w1 *= inv;
  ushort4 a = *(const ushort4*)&Po0[(size_t)row * 64 + dc];
  ushort4 b4 = *(const ushort4*)&Po1[(size_t)row * 64 + dc];
  int head = row >> 11;
  int r = row & 2047;
  int bb = head >> 4, hh = head & 15;
  size_t base = ((size_t)(bb * T_SEQ + r)) * D_MODEL + hh * HEAD_DIM + dc;
  Ob[base + 0] = bfc(w0 * bf2f(a.x) + w1 * bf2f(b4.x));
  Ob[base + 1] = bfc(w0 * bf2f(a.y) + w1 * bf2f(b4.y));
  Ob[base + 2] = bfc(w0 * bf2f(a.z) + w1 * bf2f(b4.z));
  Ob[base + 3] = bfc(w0 * bf2f(a.w) + w1 * bf2f(b4.w));
}

extern "C" void kernel_launch(void* const* d_in, const int* in_sizes, int n_in,
                              void* d_out, int out_size, void* d_ws,
                              size_t ws_size, hipStream_t stream) {
  const float* x = (const float*)d_in[0];
  const float* w_qkv = (const float*)d_in[1];
  const float* w_proj = (const float*)d_in[2];
  float* out = (float*)d_out;

  char* ws = (char*)d_ws;
  size_t off = 0;
  unsigned short* x_bf = (unsigned short*)(ws + off);
  off += (size_t)M_ROWS * D_MODEL * 2;
  unsigned short* wqkv_t = (unsigned short*)(ws + off);
  off += (size_t)D_MODEL * 3 * D_MODEL * 2;
  unsigned short* wproj_t = (unsigned short*)(ws + off);
  off += (size_t)D_MODEL * D_MODEL * 2;
  unsigned short* Qb = (unsigned short*)(ws + off);
  off += (size_t)BH_TOT * T_SEQ * HEAD_DIM * 2;
  unsigned short* Kb = (unsigned short*)(ws + off);
  off += (size_t)BH_TOT * T_SEQ * HEAD_DIM * 2;
  unsigned short* Vb = (unsigned short*)(ws + off);
  off += (size_t)BH_TOT * T_SEQ * HEAD_DIM * 2;
  unsigned short* Vt = (unsigned short*)(ws + off);
  off += (size_t)BH_TOT * T_SEQ * HEAD_DIM * 2;
  unsigned short* Ob = (unsigned short*)(ws + off);
  off += (size_t)M_ROWS * D_MODEL * 2;

  // partial buffers reuse regions dead after the qkv GEMM / transpose_v:
  unsigned short* Po0 = x_bf;              // 16.8 MB, free after gemm<0>
  unsigned short* Po1 = Vb;                // 16.8 MB, free after transpose_v
  float* Pm = (float*)wqkv_t;              // 1.05 MB  (wqkv_t free after gemm<0>)
  float* Pl = Pm + 2 * NROWS_TOT;          // 1.05 MB

  int n1 = M_ROWS * D_MODEL;
  cvt_f32_bf16<<<(n1 / 4 + 255) / 256, 256, 0, stream>>>(x, x_bf, n1);
  cvt_transpose<<<dim3(3 * D_MODEL / 32, D_MODEL / 32), 256, 0, stream>>>(
      w_qkv, wqkv_t, D_MODEL, 3 * D_MODEL);
  cvt_transpose<<<dim3(D_MODEL / 32, D_MODEL / 32), 256, 0, stream>>>(
      w_proj, wproj_t, D_MODEL, D_MODEL);

  gemm_bf16<0><<<dim3(3 * D_MODEL / 128, M_ROWS / 128), 256, 0, stream>>>(
      x_bf, wqkv_t, M_ROWS, 3 * D_MODEL, D_MODEL, Qb, Kb, Vb, nullptr);

  transpose_v<<<dim3(T_SEQ / 32, HEAD_DIM / 32, BH_TOT), 256, 0, stream>>>(Vb, Vt);

  attn_fwd<<<dim3(BH_TOT, 8, 2), 256, 0, stream>>>(Qb, Kb, Vt, Po0, Po1, Pm, Pl);

  attn_merge<<<(NROWS_TOT * 16) / 256, 256, 0, stream>>>(Po0, Po1, Pm, Pl, Ob);

  gemm_bf16<1><<<dim3(D_MODEL / 128, M_ROWS / 128), 256, 0, stream>>>(
      Ob, wproj_t, M_ROWS, D_MODEL, D_MODEL, nullptr, nullptr, nullptr, out);
}

// Round 9
// 238.846 us; speedup vs baseline: 2.3439x; 1.2210x over previous
//
#include <hip/hip_runtime.h>
#include <hip/hip_bf16.h>
#include <stdint.h>

#define D_MODEL 1024
#define N_HEADS 16
#define HEAD_DIM 64
#define B_SZ 4
#define T_SEQ 2048
#define BH_TOT (B_SZ * N_HEADS)     // 64
#define M_ROWS (B_SZ * T_SEQ)       // 8192

typedef float floatx4 __attribute__((ext_vector_type(4)));
typedef __bf16 bf16x8 __attribute__((ext_vector_type(8)));

__device__ inline unsigned short f2bf(float f) {
  union { float f; unsigned int u; } c; c.f = f;
  unsigned int u = c.u;
  unsigned int r = (u + 0x7FFFu + ((u >> 16) & 1u)) >> 16;
  return (unsigned short)r;
}

__device__ inline unsigned short bfc(float f) {  // native cvt (RNE)
  return __builtin_bit_cast(unsigned short, (__bf16)f);
}

__device__ __forceinline__ void gload16(const unsigned short* g,
                                        unsigned short* l) {
  __builtin_amdgcn_global_load_lds(
      (const __attribute__((address_space(1))) void*)g,
      (__attribute__((address_space(3))) void*)l, 16, 0, 0);
}

// ---------------- fp32 -> bf16 convert (no transpose) ----------------
__global__ void cvt_f32_bf16(const float* __restrict__ in,
                             unsigned short* __restrict__ out, int n) {
  int i = (blockIdx.x * blockDim.x + threadIdx.x) * 4;
  if (i + 3 < n) {
    float4 v = *(const float4*)(in + i);
    out[i + 0] = f2bf(v.x);
    out[i + 1] = f2bf(v.y);
    out[i + 2] = f2bf(v.z);
    out[i + 3] = f2bf(v.w);
  } else {
    for (; i < n; ++i) out[i] = f2bf(in[i]);
  }
}

// ---------------- fp32 [K][N] -> bf16 [N][K] transpose ----------------
__global__ __launch_bounds__(256) void cvt_transpose(
    const float* __restrict__ in, unsigned short* __restrict__ out,
    int K, int N) {
  __shared__ unsigned short tile[32][33];
  const int n0 = blockIdx.x * 32;
  const int k0 = blockIdx.y * 32;
  const int tx = threadIdx.x & 31;
  const int ty = threadIdx.x >> 5;  // 0..7
#pragma unroll
  for (int r = ty; r < 32; r += 8)
    tile[r][tx] = f2bf(in[(size_t)(k0 + r) * N + n0 + tx]);
  __syncthreads();
#pragma unroll
  for (int r = ty; r < 32; r += 8)
    out[(size_t)(n0 + r) * K + k0 + tx] = tile[tx][r];
}

// ---------------- bf16 V transpose: [bh][t][64] -> [bh][64][t] ----------
__global__ __launch_bounds__(256) void transpose_v(
    const unsigned short* __restrict__ Vb, unsigned short* __restrict__ Vt) {
  __shared__ unsigned short tile[32][33];
  const int t0 = blockIdx.x * 32;
  const int d0 = blockIdx.y * 32;
  const int bh = blockIdx.z;
  const unsigned short* src = Vb + (size_t)bh * T_SEQ * HEAD_DIM;
  unsigned short* dst = Vt + (size_t)bh * HEAD_DIM * T_SEQ;
  const int tx = threadIdx.x & 31;
  const int ty = threadIdx.x >> 5;
#pragma unroll
  for (int r = ty; r < 32; r += 8)
    tile[r][tx] = src[(size_t)(t0 + r) * HEAD_DIM + d0 + tx];
  __syncthreads();
#pragma unroll
  for (int r = ty; r < 32; r += 8)
    dst[(size_t)(d0 + r) * T_SEQ + t0 + tx] = tile[tx][r];
}

// ---------------- bf16 MFMA GEMM, 128x128 tile, BK=32, global_load_lds --
#define QSCALE 0.1803368801111204f  // 0.125 * log2(e)
template <int EPI>
__global__ __launch_bounds__(256) void gemm_bf16(
    const unsigned short* __restrict__ A,
    const unsigned short* __restrict__ Bt, int M, int N, int K,
    unsigned short* __restrict__ Qb, unsigned short* __restrict__ Kb,
    unsigned short* __restrict__ Vb, float* __restrict__ Cout) {
  const int bn = blockIdx.x * 128;
  const int bm = blockIdx.y * 128;
  const int tid = threadIdx.x;
  const int lane = tid & 63;
  const int w = tid >> 6;
  const int wr = w >> 1, wc = w & 1;  // 2x2 waves, each 64x64
  const int l15 = lane & 15;
  const int lg = lane >> 4;

  __shared__ unsigned short As[128 * 32];
  __shared__ unsigned short Bs[128 * 32];

  floatx4 acc[4][4] = {};

  const int srow = w * 16 + (lane >> 2);  // staging row (0..63)
  const int scol = (lane & 3) * 8;

  for (int k0 = 0; k0 < K; k0 += 32) {
    gload16(&A[(size_t)(bm + srow) * K + k0 + scol], &As[w * 512]);
    gload16(&A[(size_t)(bm + 64 + srow) * K + k0 + scol], &As[2048 + w * 512]);
    gload16(&Bt[(size_t)(bn + srow) * K + k0 + scol], &Bs[w * 512]);
    gload16(&Bt[(size_t)(bn + 64 + srow) * K + k0 + scol], &Bs[2048 + w * 512]);

    __syncthreads();

    bf16x8 af[4], bfr[4];
#pragma unroll
    for (int mt = 0; mt < 4; ++mt)
      af[mt] = *(const bf16x8*)&As[(wr * 64 + mt * 16 + l15) * 32 + lg * 8];
#pragma unroll
    for (int nt = 0; nt < 4; ++nt)
      bfr[nt] = *(const bf16x8*)&Bs[(wc * 64 + nt * 16 + l15) * 32 + lg * 8];
#pragma unroll
    for (int mt = 0; mt < 4; ++mt)
#pragma unroll
      for (int nt = 0; nt < 4; ++nt)
        acc[mt][nt] = __builtin_amdgcn_mfma_f32_16x16x32_bf16(
            af[mt], bfr[nt], acc[mt][nt], 0, 0, 0);

    __syncthreads();
  }

#pragma unroll
  for (int mt = 0; mt < 4; ++mt)
#pragma unroll
    for (int nt = 0; nt < 4; ++nt)
#pragma unroll
      for (int i = 0; i < 4; ++i) {
        int m = bm + wr * 64 + mt * 16 + lg * 4 + i;
        int n = bn + wc * 64 + nt * 16 + l15;
        float v = acc[mt][nt][i];
        if (EPI == 0) {
          int b = m >> 11;
          int t = m & (T_SEQ - 1);
          int part = n >> 10;  // 0=q 1=k 2=v
          int nn = n & (D_MODEL - 1);
          int h = nn >> 6;
          int dh = nn & 63;
          size_t idx = ((size_t)(b * N_HEADS + h) * T_SEQ + t) * HEAD_DIM + dh;
          if (part == 0)
            Qb[idx] = bfc(v * QSCALE);
          else if (part == 1)
            Kb[idx] = bfc(v);
          else
            Vb[idx] = bfc(v);
        } else {
          Cout[(size_t)m * N + n] = v;
        }
      }
}

// ---------------- causal flash attention, fine balanced pairs ----------
// Block (head, p), p in 0..15: phase 0 = q-rows [64p, 64p+64) (p+1 KV
// steps), phase 1 = mirror [2048-64(p+1), 2048-64p) (32-p steps): 33
// uniform steps/block, and within each phase ALL 4 waves (16 q-rows each)
// need the identical step count -> zero wave idling. 1024 blocks = 4/CU.
// r5-proven pipeline: stride-72 LDS, 2 barriers/step, reg-prefetch,
// exp2-domain softmax, lane-partial l, defer-max THR=8.
__global__ __launch_bounds__(256) void attn_fwd(
    const unsigned short* __restrict__ Qb, const unsigned short* __restrict__ Kb,
    const unsigned short* __restrict__ Vt, unsigned short* __restrict__ Ob) {
  const int head = blockIdx.x;  // 0..63
  const int p = blockIdx.y;     // 0..15
  const int tid = threadIdx.x;
  const int wid = tid >> 6;
  const int lane = tid & 63;
  const int l15 = lane & 15;
  const int lg = lane >> 4;
  const int b = head >> 4;
  const int h = head & 15;

  const unsigned short* Qh = Qb + (size_t)head * T_SEQ * HEAD_DIM;
  const unsigned short* Kh = Kb + (size_t)head * T_SEQ * HEAD_DIM;
  const unsigned short* Vh = Vt + (size_t)head * HEAD_DIM * T_SEQ;

  __shared__ unsigned short Ks[64 * 72];
  __shared__ unsigned short Vs[64 * 72];
  __shared__ unsigned short Plds[4][16 * 72];

  // staging map: thread -> (row, two 16B slots), stride-72 rows
  const int st_row = tid >> 2;        // 0..63
  const int st_col = (tid & 3) * 16;  // u16 units

  for (int ph = 0; ph < 2; ++ph) {
    const int rbase = (ph == 0) ? p * 64 : 2048 - 64 * (p + 1);
    const int nst = (ph == 0) ? p + 1 : 32 - p;
    const int q0 = rbase + wid * 16;

    bf16x8 qf0 = *(const bf16x8*)&Qh[(size_t)(q0 + l15) * 64 + lg * 8];
    bf16x8 qf1 = *(const bf16x8*)&Qh[(size_t)(q0 + l15) * 64 + 32 + lg * 8];

    floatx4 o[4] = {};
    float m_run[4], l_part[4];
#pragma unroll
    for (int i = 0; i < 4; ++i) {
      m_run[i] = -1e30f;
      l_part[i] = 0.f;
    }

    // prologue: prefetch chunk 0 into regs
    uint4 ka, kb2, va, vb2;
    {
      const uint4* gk = (const uint4*)&Kh[(size_t)st_row * 64 + st_col];
      ka = gk[0]; kb2 = gk[1];
      const uint4* gv = (const uint4*)&Vh[(size_t)st_row * T_SEQ + st_col];
      va = gv[0]; vb2 = gv[1];
    }

    for (int kb = 0; kb < nst; ++kb) {
      const int kbase = kb * 64;
      // write staged regs -> LDS
      *(uint4*)&Ks[st_row * 72 + st_col] = ka;
      *(uint4*)&Ks[st_row * 72 + st_col + 8] = kb2;
      *(uint4*)&Vs[st_row * 72 + st_col] = va;
      *(uint4*)&Vs[st_row * 72 + st_col + 8] = vb2;
      if (kb + 1 < nst) {  // prefetch next chunk (hides under compute)
        const int nb = kbase + 64;
        const uint4* gk = (const uint4*)&Kh[(size_t)(nb + st_row) * 64 + st_col];
        ka = gk[0]; kb2 = gk[1];
        const uint4* gv = (const uint4*)&Vh[(size_t)st_row * T_SEQ + nb + st_col];
        va = gv[0]; vb2 = gv[1];
      }
      __syncthreads();

      bf16x8 kf0[4], kf1[4];
#pragma unroll
      for (int c = 0; c < 4; ++c) {
        kf0[c] = *(const bf16x8*)&Ks[(c * 16 + l15) * 72 + lg * 8];
        kf1[c] = *(const bf16x8*)&Ks[(c * 16 + l15) * 72 + 32 + lg * 8];
      }
      bf16x8 vf[2][4];
#pragma unroll
      for (int kc = 0; kc < 2; ++kc)
#pragma unroll
        for (int d = 0; d < 4; ++d)
          vf[kc][d] = *(const bf16x8*)&Vs[(d * 16 + l15) * 72 + kc * 32 + lg * 8];

      floatx4 sc[4] = {};
      __builtin_amdgcn_s_setprio(1);
#pragma unroll
      for (int c = 0; c < 4; ++c) {
        sc[c] = __builtin_amdgcn_mfma_f32_16x16x32_bf16(qf0, kf0[c], sc[c], 0, 0, 0);
        sc[c] = __builtin_amdgcn_mfma_f32_16x16x32_bf16(qf1, kf1[c], sc[c], 0, 0, 0);
      }
      __builtin_amdgcn_s_setprio(0);

      const int kq = kbase - q0;
      if (kbase + 63 > q0) {  // causal mask (last step of each phase)
#pragma unroll
        for (int i = 0; i < 4; ++i) {
          int qoff = lg * 4 + i;
#pragma unroll
          for (int c = 0; c < 4; ++c)
            if (c * 16 + l15 + kq > qoff) sc[c][i] = -1e30f;
        }
      }

      // cheap in-lane max + ballot trigger; full reduce+rescale on trip only
      float lmax[4];
      bool need = false;
#pragma unroll
      for (int i = 0; i < 4; ++i) {
        lmax[i] = fmaxf(fmaxf(sc[0][i], sc[1][i]), fmaxf(sc[2][i], sc[3][i]));
        need |= (lmax[i] > m_run[i] + 8.0f);
      }
      if (__any(need)) {
#pragma unroll
        for (int i = 0; i < 4; ++i) {
          float pm = lmax[i];
          pm = fmaxf(pm, __shfl_xor(pm, 1));
          pm = fmaxf(pm, __shfl_xor(pm, 2));
          pm = fmaxf(pm, __shfl_xor(pm, 4));
          pm = fmaxf(pm, __shfl_xor(pm, 8));
          float mnew = fmaxf(m_run[i], pm);
          float alpha = exp2f(m_run[i] - mnew);
          m_run[i] = mnew;
          l_part[i] *= alpha;
          o[0][i] *= alpha;
          o[1][i] *= alpha;
          o[2][i] *= alpha;
          o[3][i] *= alpha;
        }
      }
      unsigned short* Pw = Plds[wid];
#pragma unroll
      for (int i = 0; i < 4; ++i) {
#pragma unroll
        for (int c = 0; c < 4; ++c) sc[c][i] = exp2f(sc[c][i] - m_run[i]);
        l_part[i] += (sc[0][i] + sc[1][i]) + (sc[2][i] + sc[3][i]);
        const int prow = lg * 4 + i;
#pragma unroll
        for (int c = 0; c < 4; ++c)
          Pw[prow * 72 + c * 16 + l15] = bfc(sc[c][i]);
      }

      __builtin_amdgcn_s_setprio(1);
      {
        const unsigned short* Pr = Plds[wid];
        bf16x8 pf0 = *(const bf16x8*)&Pr[l15 * 72 + lg * 8];
        bf16x8 pf1 = *(const bf16x8*)&Pr[l15 * 72 + 32 + lg * 8];
#pragma unroll
        for (int d = 0; d < 4; ++d) {
          o[d] = __builtin_amdgcn_mfma_f32_16x16x32_bf16(pf0, vf[0][d], o[d], 0, 0, 0);
          o[d] = __builtin_amdgcn_mfma_f32_16x16x32_bf16(pf1, vf[1][d], o[d], 0, 0, 0);
        }
      }
      __builtin_amdgcn_s_setprio(0);

      __syncthreads();
    }

    // epilogue: reduce lane-partial l, write normalized output
#pragma unroll
    for (int i = 0; i < 4; ++i) {
      float l = l_part[i];
      l += __shfl_xor(l, 1);
      l += __shfl_xor(l, 2);
      l += __shfl_xor(l, 4);
      l += __shfl_xor(l, 8);
      float inv = 1.0f / l;
      int q = q0 + lg * 4 + i;
      size_t base = ((size_t)(b * T_SEQ + q)) * D_MODEL + h * HEAD_DIM;
#pragma unroll
      for (int d = 0; d < 4; ++d) Ob[base + d * 16 + l15] = bfc(o[d][i] * inv);
    }
  }
}

extern "C" void kernel_launch(void* const* d_in, const int* in_sizes, int n_in,
                              void* d_out, int out_size, void* d_ws,
                              size_t ws_size, hipStream_t stream) {
  const float* x = (const float*)d_in[0];
  const float* w_qkv = (const float*)d_in[1];
  const float* w_proj = (const float*)d_in[2];
  float* out = (float*)d_out;

  char* ws = (char*)d_ws;
  size_t off = 0;
  unsigned short* x_bf = (unsigned short*)(ws + off);
  off += (size_t)M_ROWS * D_MODEL * 2;
  unsigned short* wqkv_t = (unsigned short*)(ws + off);
  off += (size_t)D_MODEL * 3 * D_MODEL * 2;
  unsigned short* wproj_t = (unsigned short*)(ws + off);
  off += (size_t)D_MODEL * D_MODEL * 2;
  unsigned short* Qb = (unsigned short*)(ws + off);
  off += (size_t)BH_TOT * T_SEQ * HEAD_DIM * 2;
  unsigned short* Kb = (unsigned short*)(ws + off);
  off += (size_t)BH_TOT * T_SEQ * HEAD_DIM * 2;
  unsigned short* Vb = (unsigned short*)(ws + off);
  off += (size_t)BH_TOT * T_SEQ * HEAD_DIM * 2;
  unsigned short* Vt = (unsigned short*)(ws + off);
  off += (size_t)BH_TOT * T_SEQ * HEAD_DIM * 2;
  unsigned short* Ob = (unsigned short*)(ws + off);
  off += (size_t)M_ROWS * D_MODEL * 2;

  int n1 = M_ROWS * D_MODEL;
  cvt_f32_bf16<<<(n1 / 4 + 255) / 256, 256, 0, stream>>>(x, x_bf, n1);
  cvt_transpose<<<dim3(3 * D_MODEL / 32, D_MODEL / 32), 256, 0, stream>>>(
      w_qkv, wqkv_t, D_MODEL, 3 * D_MODEL);
  cvt_transpose<<<dim3(D_MODEL / 32, D_MODEL / 32), 256, 0, stream>>>(
      w_proj, wproj_t, D_MODEL, D_MODEL);

  gemm_bf16<0><<<dim3(3 * D_MODEL / 128, M_ROWS / 128), 256, 0, stream>>>(
      x_bf, wqkv_t, M_ROWS, 3 * D_MODEL, D_MODEL, Qb, Kb, Vb, nullptr);

  transpose_v<<<dim3(T_SEQ / 32, HEAD_DIM / 32, BH_TOT), 256, 0, stream>>>(Vb, Vt);

  attn_fwd<<<dim3(BH_TOT, 16), 256, 0, stream>>>(Qb, Kb, Vt, Ob);

  gemm_bf16<1><<<dim3(D_MODEL / 128, M_ROWS / 128), 256, 0, stream>>>(
      Ob, wproj_t, M_ROWS, D_MODEL, D_MODEL, nullptr, nullptr, nullptr, out);
}

// Round 10
// 209.616 us; speedup vs baseline: 2.6707x; 1.1394x over previous
//
#include <hip/hip_runtime.h>
#include <hip/hip_bf16.h>
#include <stdint.h>

#define D_MODEL 1024
#define N_HEADS 16
#define HEAD_DIM 64
#define B_SZ 4
#define T_SEQ 2048
#define BH_TOT (B_SZ * N_HEADS)     // 64
#define M_ROWS (B_SZ * T_SEQ)       // 8192

typedef float floatx4 __attribute__((ext_vector_type(4)));
typedef __bf16 bf16x8 __attribute__((ext_vector_type(8)));

#if __has_builtin(__builtin_amdgcn_exp2f)
#define EXP2(x) __builtin_amdgcn_exp2f(x)
#else
#define EXP2(x) exp2f(x)
#endif

__device__ inline unsigned short f2bf(float f) {
  union { float f; unsigned int u; } c; c.f = f;
  unsigned int u = c.u;
  unsigned int r = (u + 0x7FFFu + ((u >> 16) & 1u)) >> 16;
  return (unsigned short)r;
}

__device__ inline unsigned short bfc(float f) {  // native cvt (RNE)
  return __builtin_bit_cast(unsigned short, (__bf16)f);
}

__device__ inline unsigned int pk2(float lo, float hi) {  // 2xbf16 in u32
  return (unsigned int)bfc(lo) | ((unsigned int)bfc(hi) << 16);
}

__device__ __forceinline__ void gload16(const unsigned short* g,
                                        unsigned short* l) {
  __builtin_amdgcn_global_load_lds(
      (const __attribute__((address_space(1))) void*)g,
      (__attribute__((address_space(3))) void*)l, 16, 0, 0);
}

// ---------------- fp32 -> bf16 convert (no transpose) ----------------
__global__ void cvt_f32_bf16(const float* __restrict__ in,
                             unsigned short* __restrict__ out, int n) {
  int i = (blockIdx.x * blockDim.x + threadIdx.x) * 4;
  if (i + 3 < n) {
    float4 v = *(const float4*)(in + i);
    out[i + 0] = f2bf(v.x);
    out[i + 1] = f2bf(v.y);
    out[i + 2] = f2bf(v.z);
    out[i + 3] = f2bf(v.w);
  } else {
    for (; i < n; ++i) out[i] = f2bf(in[i]);
  }
}

// ---------------- fp32 [K][N] -> bf16 [N][K] transpose ----------------
__global__ __launch_bounds__(256) void cvt_transpose(
    const float* __restrict__ in, unsigned short* __restrict__ out,
    int K, int N) {
  __shared__ unsigned short tile[32][33];
  const int n0 = blockIdx.x * 32;
  const int k0 = blockIdx.y * 32;
  const int tx = threadIdx.x & 31;
  const int ty = threadIdx.x >> 5;  // 0..7
#pragma unroll
  for (int r = ty; r < 32; r += 8)
    tile[r][tx] = f2bf(in[(size_t)(k0 + r) * N + n0 + tx]);
  __syncthreads();
#pragma unroll
  for (int r = ty; r < 32; r += 8)
    out[(size_t)(n0 + r) * K + k0 + tx] = tile[tx][r];
}

// ---------------- bf16 V transpose: [bh][t][64] -> [bh][64][t] ----------
__global__ __launch_bounds__(256) void transpose_v(
    const unsigned short* __restrict__ Vb, unsigned short* __restrict__ Vt) {
  __shared__ unsigned short tile[32][33];
  const int t0 = blockIdx.x * 32;
  const int d0 = blockIdx.y * 32;
  const int bh = blockIdx.z;
  const unsigned short* src = Vb + (size_t)bh * T_SEQ * HEAD_DIM;
  unsigned short* dst = Vt + (size_t)bh * HEAD_DIM * T_SEQ;
  const int tx = threadIdx.x & 31;
  const int ty = threadIdx.x >> 5;
#pragma unroll
  for (int r = ty; r < 32; r += 8)
    tile[r][tx] = src[(size_t)(t0 + r) * HEAD_DIM + d0 + tx];
  __syncthreads();
#pragma unroll
  for (int r = ty; r < 32; r += 8)
    dst[(size_t)(d0 + r) * T_SEQ + t0 + tx] = tile[tx][r];
}

// ---------------- bf16 MFMA GEMM, 128x128 tile, BK=32, global_load_lds --
#define QSCALE 0.1803368801111204f  // 0.125 * log2(e)
template <int EPI>
__global__ __launch_bounds__(256) void gemm_bf16(
    const unsigned short* __restrict__ A,
    const unsigned short* __restrict__ Bt, int M, int N, int K,
    unsigned short* __restrict__ Qb, unsigned short* __restrict__ Kb,
    unsigned short* __restrict__ Vb, float* __restrict__ Cout) {
  const int bn = blockIdx.x * 128;
  const int bm = blockIdx.y * 128;
  const int tid = threadIdx.x;
  const int lane = tid & 63;
  const int w = tid >> 6;
  const int wr = w >> 1, wc = w & 1;  // 2x2 waves, each 64x64
  const int l15 = lane & 15;
  const int lg = lane >> 4;

  __shared__ unsigned short As[128 * 32];
  __shared__ unsigned short Bs[128 * 32];

  floatx4 acc[4][4] = {};

  const int srow = w * 16 + (lane >> 2);  // staging row (0..63)
  const int scol = (lane & 3) * 8;

  for (int k0 = 0; k0 < K; k0 += 32) {
    gload16(&A[(size_t)(bm + srow) * K + k0 + scol], &As[w * 512]);
    gload16(&A[(size_t)(bm + 64 + srow) * K + k0 + scol], &As[2048 + w * 512]);
    gload16(&Bt[(size_t)(bn + srow) * K + k0 + scol], &Bs[w * 512]);
    gload16(&Bt[(size_t)(bn + 64 + srow) * K + k0 + scol], &Bs[2048 + w * 512]);

    __syncthreads();

    bf16x8 af[4], bfr[4];
#pragma unroll
    for (int mt = 0; mt < 4; ++mt)
      af[mt] = *(const bf16x8*)&As[(wr * 64 + mt * 16 + l15) * 32 + lg * 8];
#pragma unroll
    for (int nt = 0; nt < 4; ++nt)
      bfr[nt] = *(const bf16x8*)&Bs[(wc * 64 + nt * 16 + l15) * 32 + lg * 8];
#pragma unroll
    for (int mt = 0; mt < 4; ++mt)
#pragma unroll
      for (int nt = 0; nt < 4; ++nt)
        acc[mt][nt] = __builtin_amdgcn_mfma_f32_16x16x32_bf16(
            af[mt], bfr[nt], acc[mt][nt], 0, 0, 0);

    __syncthreads();
  }

#pragma unroll
  for (int mt = 0; mt < 4; ++mt)
#pragma unroll
    for (int nt = 0; nt < 4; ++nt)
#pragma unroll
      for (int i = 0; i < 4; ++i) {
        int m = bm + wr * 64 + mt * 16 + lg * 4 + i;
        int n = bn + wc * 64 + nt * 16 + l15;
        float v = acc[mt][nt][i];
        if (EPI == 0) {
          int b = m >> 11;
          int t = m & (T_SEQ - 1);
          int part = n >> 10;  // 0=q 1=k 2=v
          int nn = n & (D_MODEL - 1);
          int h = nn >> 6;
          int dh = nn & 63;
          size_t idx = ((size_t)(b * N_HEADS + h) * T_SEQ + t) * HEAD_DIM + dh;
          if (part == 0)
            Qb[idx] = bfc(v * QSCALE);
          else if (part == 1)
            Kb[idx] = bfc(v);
          else
            Vb[idx] = bfc(v);
        } else {
          Cout[(size_t)m * N + n] = v;
        }
      }
}

// ---------------- causal flash attention, swapped-QK^T ----------------
// r5 geometry: block (head, p in 0..7), phase 0 = rows [128p,128p+128),
// phase 1 = mirror; 34 uniform steps. 4 waves x 32 q-rows (2 tiles).
// Swapped MFMA: S^T = mfma(K,Q) -> each lane owns ONE q-row (col=l15):
// m/l are per-lane scalars, stats in-lane, NO cross-lane shuffles in the
// steady path. P packed to u32 pairs, 4x ds_write_b64 into XOR-swizzled
// [16][64] tile (conflict-free), read back as 2x b128 for PV with
// A = V^T fragments (from Vt). Raw v_exp_f32 for exp2.
__global__ __launch_bounds__(256) void attn_fwd(
    const unsigned short* __restrict__ Qb, const unsigned short* __restrict__ Kb,
    const unsigned short* __restrict__ Vt, unsigned short* __restrict__ Ob) {
  const int head = blockIdx.x;  // 0..63
  const int p = blockIdx.y;     // 0..7
  const int tid = threadIdx.x;
  const int wid = tid >> 6;
  const int lane = tid & 63;
  const int l15 = lane & 15;
  const int lg = lane >> 4;
  const int l7 = l15 & 7;
  const int b = head >> 4;
  const int h = head & 15;

  const unsigned short* Qh = Qb + (size_t)head * T_SEQ * HEAD_DIM;
  const unsigned short* Kh = Kb + (size_t)head * T_SEQ * HEAD_DIM;
  const unsigned short* Vh = Vt + (size_t)head * HEAD_DIM * T_SEQ;

  __shared__ unsigned short Ks[64 * 72];
  __shared__ unsigned short Vs[64 * 72];
  __shared__ unsigned short Ps[4 * 2 * 16 * 64];  // wave-private, swizzled

  // staging map (stride-72, r5-proven)
  const int st_row = tid >> 2;
  const int st_col = (tid & 3) * 16;

  // hoisted LDS offsets (u16 units)
  int kfo0[4], kfo1[4], vfo[2][4];
#pragma unroll
  for (int c = 0; c < 4; ++c) {
    kfo0[c] = (c * 16 + l15) * 72 + lg * 8;
    kfo1[c] = kfo0[c] + 32;
  }
#pragma unroll
  for (int kc = 0; kc < 2; ++kc)
#pragma unroll
    for (int d = 0; d < 4; ++d)
      vfo[kc][d] = (d * 16 + l15) * 72 + kc * 32 + lg * 8;
  // P write: row=l15 (q), cols c*16+lg*4.. as b64 at swizzled slot
  int pwo[4];
#pragma unroll
  for (int c = 0; c < 4; ++c)
    pwo[c] = l15 * 64 + (((2 * c + (lg >> 1)) ^ l7) << 3) + (lg & 1) * 4;
  // P read: row=l15, 16B slot (4*kc+lg)^l7
  const int pro0 = l15 * 64 + (((4 * 0 + lg) ^ l7) << 3);
  const int pro1 = l15 * 64 + (((4 * 1 + lg) ^ l7) << 3);

  for (int ph = 0; ph < 2; ++ph) {
    const int rbase = (ph == 0) ? p * 128 : 2048 - 128 * (p + 1);
    const int nst = (ph == 0) ? 2 * p + 2 : 32 - 2 * p;
    const int q0 = rbase + wid * 32;

    bf16x8 qf[2][2];
#pragma unroll
    for (int t = 0; t < 2; ++t)
#pragma unroll
      for (int c = 0; c < 2; ++c)
        qf[t][c] = *(const bf16x8*)&Qh[(size_t)(q0 + t * 16 + l15) * 64 +
                                       c * 32 + lg * 8];

    floatx4 o[2][4] = {};
    float m_run[2] = {-1e30f, -1e30f};
    float l_part[2] = {0.f, 0.f};

    // prologue: prefetch chunk 0 into regs
    uint4 ka, kb2, va, vb2;
    {
      const uint4* gk = (const uint4*)&Kh[(size_t)st_row * 64 + st_col];
      ka = gk[0]; kb2 = gk[1];
      const uint4* gv = (const uint4*)&Vh[(size_t)st_row * T_SEQ + st_col];
      va = gv[0]; vb2 = gv[1];
    }

    for (int kb = 0; kb < nst; ++kb) {
      const int kbase = kb * 64;
      *(uint4*)&Ks[st_row * 72 + st_col] = ka;
      *(uint4*)&Ks[st_row * 72 + st_col + 8] = kb2;
      *(uint4*)&Vs[st_row * 72 + st_col] = va;
      *(uint4*)&Vs[st_row * 72 + st_col + 8] = vb2;
      if (kb + 1 < nst) {  // prefetch next chunk (hides under compute)
        const int nb = kbase + 64;
        const uint4* gk = (const uint4*)&Kh[(size_t)(nb + st_row) * 64 + st_col];
        ka = gk[0]; kb2 = gk[1];
        const uint4* gv = (const uint4*)&Vh[(size_t)st_row * T_SEQ + nb + st_col];
        va = gv[0]; vb2 = gv[1];
      }
      __syncthreads();

      if (kbase <= q0 + 31) {  // causal work remains for this wave
        bf16x8 kf0[4], kf1[4];
#pragma unroll
        for (int c = 0; c < 4; ++c) {
          kf0[c] = *(const bf16x8*)&Ks[kfo0[c]];
          kf1[c] = *(const bf16x8*)&Ks[kfo1[c]];
        }
        bf16x8 vf[2][4];
#pragma unroll
        for (int kc = 0; kc < 2; ++kc)
#pragma unroll
          for (int d = 0; d < 4; ++d) vf[kc][d] = *(const bf16x8*)&Vs[vfo[kc][d]];

        // S^T = K . Q^T : D[row = k_local = lg*4+i, col = q_local = l15]
        floatx4 st_[2][4] = {};
        __builtin_amdgcn_s_setprio(1);
#pragma unroll
        for (int c = 0; c < 4; ++c) {
          st_[0][c] = __builtin_amdgcn_mfma_f32_16x16x32_bf16(kf0[c], qf[0][0], st_[0][c], 0, 0, 0);
          st_[0][c] = __builtin_amdgcn_mfma_f32_16x16x32_bf16(kf1[c], qf[0][1], st_[0][c], 0, 0, 0);
          st_[1][c] = __builtin_amdgcn_mfma_f32_16x16x32_bf16(kf0[c], qf[1][0], st_[1][c], 0, 0, 0);
          st_[1][c] = __builtin_amdgcn_mfma_f32_16x16x32_bf16(kf1[c], qf[1][1], st_[1][c], 0, 0, 0);
        }
        __builtin_amdgcn_s_setprio(0);

        if (kbase + 63 > q0) {  // causal mask: k_local > q - kbase
#pragma unroll
          for (int t = 0; t < 2; ++t) {
            const int thr = q0 + t * 16 + l15 - kbase;
#pragma unroll
            for (int c = 0; c < 4; ++c)
#pragma unroll
              for (int i = 0; i < 4; ++i)
                if (c * 16 + lg * 4 + i > thr) st_[t][c][i] = -1e30f;
          }
        }

        // in-lane stats (lane owns one q-row), defer-max THR=8
        float lmax[2];
        bool need = false;
#pragma unroll
        for (int t = 0; t < 2; ++t) {
          float v0 = fmaxf(fmaxf(st_[t][0][0], st_[t][0][1]),
                           fmaxf(st_[t][0][2], st_[t][0][3]));
          float v1 = fmaxf(fmaxf(st_[t][1][0], st_[t][1][1]),
                           fmaxf(st_[t][1][2], st_[t][1][3]));
          float v2 = fmaxf(fmaxf(st_[t][2][0], st_[t][2][1]),
                           fmaxf(st_[t][2][2], st_[t][2][3]));
          float v3 = fmaxf(fmaxf(st_[t][3][0], st_[t][3][1]),
                           fmaxf(st_[t][3][2], st_[t][3][3]));
          lmax[t] = fmaxf(fmaxf(v0, v1), fmaxf(v2, v3));
          need |= (lmax[t] > m_run[t] + 8.0f);
        }
        if (__any(need)) {
#pragma unroll
          for (int t = 0; t < 2; ++t) {
            float pm = lmax[t];
            pm = fmaxf(pm, __shfl_xor(pm, 16));
            pm = fmaxf(pm, __shfl_xor(pm, 32));
            float mnew = fmaxf(m_run[t], pm);
            float alpha = EXP2(m_run[t] - mnew);
            m_run[t] = mnew;
            l_part[t] *= alpha;
#pragma unroll
            for (int c = 0; c < 4; ++c) o[t][c] *= alpha;
          }
        }

#pragma unroll
        for (int t = 0; t < 2; ++t) {
          const int tb = (wid * 2 + t) * 1024;
          float sum = 0.f;
#pragma unroll
          for (int c = 0; c < 4; ++c) {
#pragma unroll
            for (int i = 0; i < 4; ++i) {
              st_[t][c][i] = EXP2(st_[t][c][i] - m_run[t]);
              sum += st_[t][c][i];
            }
            uint2 w;
            w.x = pk2(st_[t][c][0], st_[t][c][1]);
            w.y = pk2(st_[t][c][2], st_[t][c][3]);
            *(uint2*)&Ps[tb + pwo[c]] = w;  // ds_write_b64, swizzled
          }
          l_part[t] += sum;
        }

        // O^T += V^T . P^T : A = vf (row=d), B = P^T (col=q)
        __builtin_amdgcn_s_setprio(1);
#pragma unroll
        for (int t = 0; t < 2; ++t) {
          const int tb = (wid * 2 + t) * 1024;
          bf16x8 pb0 = *(const bf16x8*)&Ps[tb + pro0];
          bf16x8 pb1 = *(const bf16x8*)&Ps[tb + pro1];
#pragma unroll
          for (int dt = 0; dt < 4; ++dt) {
            o[t][dt] = __builtin_amdgcn_mfma_f32_16x16x32_bf16(vf[0][dt], pb0, o[t][dt], 0, 0, 0);
            o[t][dt] = __builtin_amdgcn_mfma_f32_16x16x32_bf16(vf[1][dt], pb1, o[t][dt], 0, 0, 0);
          }
        }
        __builtin_amdgcn_s_setprio(0);
      }

      __syncthreads();
    }

    // epilogue: row l (4 lg-lane partials) via 2 shuffles; write O
#pragma unroll
    for (int t = 0; t < 2; ++t) {
      float l = l_part[t];
      l += __shfl_xor(l, 16);
      l += __shfl_xor(l, 32);
      float inv = 1.0f / l;
      int q = q0 + t * 16 + l15;
      size_t base = ((size_t)(b * T_SEQ + q)) * D_MODEL + h * HEAD_DIM;
#pragma unroll
      for (int dt = 0; dt < 4; ++dt) {
        unsigned int u0 = pk2(o[t][dt][0] * inv, o[t][dt][1] * inv);
        unsigned int u1 = pk2(o[t][dt][2] * inv, o[t][dt][3] * inv);
        *(unsigned int*)&Ob[base + dt * 16 + lg * 4] = u0;
        *(unsigned int*)&Ob[base + dt * 16 + lg * 4 + 2] = u1;
      }
    }
  }
}

extern "C" void kernel_launch(void* const* d_in, const int* in_sizes, int n_in,
                              void* d_out, int out_size, void* d_ws,
                              size_t ws_size, hipStream_t stream) {
  const float* x = (const float*)d_in[0];
  const float* w_qkv = (const float*)d_in[1];
  const float* w_proj = (const float*)d_in[2];
  float* out = (float*)d_out;

  char* ws = (char*)d_ws;
  size_t off = 0;
  unsigned short* x_bf = (unsigned short*)(ws + off);
  off += (size_t)M_ROWS * D_MODEL * 2;
  unsigned short* wqkv_t = (unsigned short*)(ws + off);
  off += (size_t)D_MODEL * 3 * D_MODEL * 2;
  unsigned short* wproj_t = (unsigned short*)(ws + off);
  off += (size_t)D_MODEL * D_MODEL * 2;
  unsigned short* Qb = (unsigned short*)(ws + off);
  off += (size_t)BH_TOT * T_SEQ * HEAD_DIM * 2;
  unsigned short* Kb = (unsigned short*)(ws + off);
  off += (size_t)BH_TOT * T_SEQ * HEAD_DIM * 2;
  unsigned short* Vb = (unsigned short*)(ws + off);
  off += (size_t)BH_TOT * T_SEQ * HEAD_DIM * 2;
  unsigned short* Vt = (unsigned short*)(ws + off);
  off += (size_t)BH_TOT * T_SEQ * HEAD_DIM * 2;
  unsigned short* Ob = (unsigned short*)(ws + off);
  off += (size_t)M_ROWS * D_MODEL * 2;

  int n1 = M_ROWS * D_MODEL;
  cvt_f32_bf16<<<(n1 / 4 + 255) / 256, 256, 0, stream>>>(x, x_bf, n1);
  cvt_transpose<<<dim3(3 * D_MODEL / 32, D_MODEL / 32), 256, 0, stream>>>(
      w_qkv, wqkv_t, D_MODEL, 3 * D_MODEL);
  cvt_transpose<<<dim3(D_MODEL / 32, D_MODEL / 32), 256, 0, stream>>>(
      w_proj, wproj_t, D_MODEL, D_MODEL);

  gemm_bf16<0><<<dim3(3 * D_MODEL / 128, M_ROWS / 128), 256, 0, stream>>>(
      x_bf, wqkv_t, M_ROWS, 3 * D_MODEL, D_MODEL, Qb, Kb, Vb, nullptr);

  transpose_v<<<dim3(T_SEQ / 32, HEAD_DIM / 32, BH_TOT), 256, 0, stream>>>(Vb, Vt);

  attn_fwd<<<dim3(BH_TOT, 8), 256, 0, stream>>>(Qb, Kb, Vt, Ob);

  gemm_bf16<1><<<dim3(D_MODEL / 128, M_ROWS / 128), 256, 0, stream>>>(
      Ob, wproj_t, M_ROWS, D_MODEL, D_MODEL, nullptr, nullptr, nullptr, out);
}

// Round 11
// 198.354 us; speedup vs baseline: 2.8223x; 1.0568x over previous
//
#include <hip/hip_runtime.h>
#include <hip/hip_bf16.h>
#include <stdint.h>

#define D_MODEL 1024
#define N_HEADS 16
#define HEAD_DIM 64
#define B_SZ 4
#define T_SEQ 2048
#define BH_TOT (B_SZ * N_HEADS)     // 64
#define M_ROWS (B_SZ * T_SEQ)       // 8192

typedef float floatx4 __attribute__((ext_vector_type(4)));
typedef __bf16 bf16x8 __attribute__((ext_vector_type(8)));

#if __has_builtin(__builtin_amdgcn_exp2f)
#define EXP2(x) __builtin_amdgcn_exp2f(x)
#else
#define EXP2(x) exp2f(x)
#endif

__device__ inline unsigned short f2bf(float f) {
  union { float f; unsigned int u; } c; c.f = f;
  unsigned int u = c.u;
  unsigned int r = (u + 0x7FFFu + ((u >> 16) & 1u)) >> 16;
  return (unsigned short)r;
}

__device__ inline unsigned short bfc(float f) {  // native cvt (RNE)
  return __builtin_bit_cast(unsigned short, (__bf16)f);
}

__device__ inline unsigned int pk2(float lo, float hi) {  // 2xbf16 in u32
  return (unsigned int)bfc(lo) | ((unsigned int)bfc(hi) << 16);
}

__device__ __forceinline__ void gload16(const unsigned short* g,
                                        unsigned short* l) {
  __builtin_amdgcn_global_load_lds(
      (const __attribute__((address_space(1))) void*)g,
      (__attribute__((address_space(3))) void*)l, 16, 0, 0);
}

// ---------------- fp32 -> bf16 convert (no transpose) ----------------
__global__ void cvt_f32_bf16(const float* __restrict__ in,
                             unsigned short* __restrict__ out, int n) {
  int i = (blockIdx.x * blockDim.x + threadIdx.x) * 4;
  if (i + 3 < n) {
    float4 v = *(const float4*)(in + i);
    out[i + 0] = f2bf(v.x);
    out[i + 1] = f2bf(v.y);
    out[i + 2] = f2bf(v.z);
    out[i + 3] = f2bf(v.w);
  } else {
    for (; i < n; ++i) out[i] = f2bf(in[i]);
  }
}

// ---------------- fp32 [K][N] -> bf16 [N][K] transpose ----------------
__global__ __launch_bounds__(256) void cvt_transpose(
    const float* __restrict__ in, unsigned short* __restrict__ out,
    int K, int N) {
  __shared__ unsigned short tile[32][33];
  const int n0 = blockIdx.x * 32;
  const int k0 = blockIdx.y * 32;
  const int tx = threadIdx.x & 31;
  const int ty = threadIdx.x >> 5;  // 0..7
#pragma unroll
  for (int r = ty; r < 32; r += 8)
    tile[r][tx] = f2bf(in[(size_t)(k0 + r) * N + n0 + tx]);
  __syncthreads();
#pragma unroll
  for (int r = ty; r < 32; r += 8)
    out[(size_t)(n0 + r) * K + k0 + tx] = tile[tx][r];
}

// ---------------- bf16 MFMA GEMM, 128x128 tile, BK=32, global_load_lds --
// EPI 0: qkv epilogue. Q scaled by 0.125*log2e -> Qb[bh][t][64];
//        K -> Kb[bh][t][64]; V written TRANSPOSED to Vt[bh][64][t]
//        (ushort4 over the 4 consecutive t of acc[i]) - fuses transpose_v.
#define QSCALE 0.1803368801111204f  // 0.125 * log2(e)
template <int EPI>
__global__ __launch_bounds__(256) void gemm_bf16(
    const unsigned short* __restrict__ A,
    const unsigned short* __restrict__ Bt, int M, int N, int K,
    unsigned short* __restrict__ Qb, unsigned short* __restrict__ Kb,
    unsigned short* __restrict__ Vt, float* __restrict__ Cout) {
  const int bn = blockIdx.x * 128;
  const int bm = blockIdx.y * 128;
  const int tid = threadIdx.x;
  const int lane = tid & 63;
  const int w = tid >> 6;
  const int wr = w >> 1, wc = w & 1;  // 2x2 waves, each 64x64
  const int l15 = lane & 15;
  const int lg = lane >> 4;

  __shared__ unsigned short As[128 * 32];
  __shared__ unsigned short Bs[128 * 32];

  floatx4 acc[4][4] = {};

  const int srow = w * 16 + (lane >> 2);  // staging row (0..63)
  const int scol = (lane & 3) * 8;

  for (int k0 = 0; k0 < K; k0 += 32) {
    gload16(&A[(size_t)(bm + srow) * K + k0 + scol], &As[w * 512]);
    gload16(&A[(size_t)(bm + 64 + srow) * K + k0 + scol], &As[2048 + w * 512]);
    gload16(&Bt[(size_t)(bn + srow) * K + k0 + scol], &Bs[w * 512]);
    gload16(&Bt[(size_t)(bn + 64 + srow) * K + k0 + scol], &Bs[2048 + w * 512]);

    __syncthreads();

    bf16x8 af[4], bfr[4];
#pragma unroll
    for (int mt = 0; mt < 4; ++mt)
      af[mt] = *(const bf16x8*)&As[(wr * 64 + mt * 16 + l15) * 32 + lg * 8];
#pragma unroll
    for (int nt = 0; nt < 4; ++nt)
      bfr[nt] = *(const bf16x8*)&Bs[(wc * 64 + nt * 16 + l15) * 32 + lg * 8];
#pragma unroll
    for (int mt = 0; mt < 4; ++mt)
#pragma unroll
      for (int nt = 0; nt < 4; ++nt)
        acc[mt][nt] = __builtin_amdgcn_mfma_f32_16x16x32_bf16(
            af[mt], bfr[nt], acc[mt][nt], 0, 0, 0);

    __syncthreads();
  }

#pragma unroll
  for (int mt = 0; mt < 4; ++mt)
#pragma unroll
    for (int nt = 0; nt < 4; ++nt) {
      const int n = bn + wc * 64 + nt * 16 + l15;
      const int m0 = bm + wr * 64 + mt * 16 + lg * 4;
      if (EPI == 0 && (n >> 10) == 2) {
        // V: write transposed, vectorized over the 4 consecutive t
        int b = m0 >> 11;
        int t = m0 & (T_SEQ - 1);
        int nn = n & (D_MODEL - 1);
        int h = nn >> 6;
        int dh = nn & 63;
        ushort4 v4;
        v4.x = bfc(acc[mt][nt][0]);
        v4.y = bfc(acc[mt][nt][1]);
        v4.z = bfc(acc[mt][nt][2]);
        v4.w = bfc(acc[mt][nt][3]);
        *(ushort4*)&Vt[((size_t)((b * N_HEADS + h) * HEAD_DIM) + dh) * T_SEQ +
                       t] = v4;
      } else {
#pragma unroll
        for (int i = 0; i < 4; ++i) {
          int m = m0 + i;
          float v = acc[mt][nt][i];
          if (EPI == 0) {
            int b = m >> 11;
            int t = m & (T_SEQ - 1);
            int part = n >> 10;  // 0=q 1=k
            int nn = n & (D_MODEL - 1);
            int h = nn >> 6;
            int dh = nn & 63;
            size_t idx =
                ((size_t)(b * N_HEADS + h) * T_SEQ + t) * HEAD_DIM + dh;
            if (part == 0)
              Qb[idx] = bfc(v * QSCALE);
            else
              Kb[idx] = bfc(v);
          } else {
            Cout[(size_t)m * N + n] = v;
          }
        }
      }
    }
}

// ---------------- causal flash attention, swapped-QK^T + gload_lds ------
// r5 geometry: block (head, p in 0..7), phase 0 = rows [128p,128p+128),
// phase 1 = mirror; 34 uniform steps. 4 waves x 32 q-rows.
// K/V staged via global_load_lds into double-buffered linear [64][64]
// tiles with PRE-SWIZZLED global source (LDS[row][x] holds global slot
// x^(row&7)); reads use the same XOR -> conflict-free (r6-proven).
// ONE barrier/step: barrier -> issue next-step loads to buf^1 -> compute.
// Swapped MFMA S^T = mfma(K,Q): lane owns one q-row, in-lane softmax,
// defer-max THR=8, P via 4x ds_write_b64 to swizzled tile, PV with V^T.
__global__ __launch_bounds__(256) void attn_fwd(
    const unsigned short* __restrict__ Qb, const unsigned short* __restrict__ Kb,
    const unsigned short* __restrict__ Vt, unsigned short* __restrict__ Ob) {
  const int head = blockIdx.x;  // 0..63
  const int p = blockIdx.y;     // 0..7
  const int tid = threadIdx.x;
  const int wid = tid >> 6;
  const int lane = tid & 63;
  const int l15 = lane & 15;
  const int lg = lane >> 4;
  const int l7 = l15 & 7;
  const int b = head >> 4;
  const int h = head & 15;

  const unsigned short* Qh = Qb + (size_t)head * T_SEQ * HEAD_DIM;
  const unsigned short* Kh = Kb + (size_t)head * T_SEQ * HEAD_DIM;
  const unsigned short* Vh = Vt + (size_t)head * HEAD_DIM * T_SEQ;

  __shared__ unsigned short Ks[2][64 * 64];
  __shared__ unsigned short Vs[2][64 * 64];
  __shared__ unsigned short Ps[4 * 2 * 16 * 64];  // wave-private, swizzled

  // gload_lds staging: wave wid covers rows [16*wid, 16*wid+16) as two
  // 1KB chunks; lane source col slot = (lane&7)^(lane>>3) (inverse swz).
  const int swz8 = (((lane & 7) ^ (lane >> 3)) << 3);  // u16 units
  const int srow = wid * 16 + (lane >> 3);
  const size_t kLane0 = (size_t)srow * HEAD_DIM + swz8;
  const size_t kLane1 = (size_t)(srow + 8) * HEAD_DIM + swz8;
  const size_t vLane0 = (size_t)srow * T_SEQ + swz8;
  const size_t vLane1 = (size_t)(srow + 8) * T_SEQ + swz8;
  const int ldsW = wid * 1024;  // u16: wave's 2KB region per tile

  // hoisted fragment read offsets (u16 units)
  int kfo0[4], kfo1[4], vfo[2][4];
#pragma unroll
  for (int c = 0; c < 4; ++c) {
    kfo0[c] = (c * 16 + l15) * 64 + ((lg ^ l7) << 3);
    kfo1[c] = (c * 16 + l15) * 64 + (((4 + lg) ^ l7) << 3);
  }
#pragma unroll
  for (int kc = 0; kc < 2; ++kc)
#pragma unroll
    for (int d = 0; d < 4; ++d)
      vfo[kc][d] = (d * 16 + l15) * 64 + (((kc * 4 + lg) ^ l7) << 3);
  // P write: row=l15 (q), 4x b64 at swizzled slots
  int pwo[4];
#pragma unroll
  for (int c = 0; c < 4; ++c)
    pwo[c] = l15 * 64 + (((2 * c + (lg >> 1)) ^ l7) << 3) + (lg & 1) * 4;
  const int pro0 = l15 * 64 + ((lg ^ l7) << 3);
  const int pro1 = l15 * 64 + (((4 + lg) ^ l7) << 3);

  for (int ph = 0; ph < 2; ++ph) {
    const int rbase = (ph == 0) ? p * 128 : 2048 - 128 * (p + 1);
    const int nst = (ph == 0) ? 2 * p + 2 : 32 - 2 * p;
    const int q0 = rbase + wid * 32;

    bf16x8 qf[2][2];
#pragma unroll
    for (int t = 0; t < 2; ++t)
#pragma unroll
      for (int c = 0; c < 2; ++c)
        qf[t][c] = *(const bf16x8*)&Qh[(size_t)(q0 + t * 16 + l15) * 64 +
                                       c * 32 + lg * 8];

    floatx4 o[2][4] = {};
    float m_run[2] = {-1e30f, -1e30f};
    float l_part[2] = {0.f, 0.f};

    __syncthreads();  // previous phase's reads fully done before restaging
    // prologue: issue chunk 0 into buffer 0
    gload16(Kh + kLane0, &Ks[0][ldsW]);
    gload16(Kh + kLane1, &Ks[0][ldsW + 512]);
    gload16(Vh + vLane0, &Vs[0][ldsW]);
    gload16(Vh + vLane1, &Vs[0][ldsW + 512]);

    int cur = 0;
    for (int kb = 0; kb < nst; ++kb, cur ^= 1) {
      const int kbase = kb * 64;
      __syncthreads();  // drains vmcnt -> buf[cur] fully staged, all waves

      if (kb + 1 < nst) {  // issue next chunk into idle buffer (hidden)
        const size_t ko = (size_t)(kbase + 64) * HEAD_DIM;
        const int vo = kbase + 64;
        gload16(Kh + ko + kLane0, &Ks[cur ^ 1][ldsW]);
        gload16(Kh + ko + kLane1, &Ks[cur ^ 1][ldsW + 512]);
        gload16(Vh + vo + vLane0, &Vs[cur ^ 1][ldsW]);
        gload16(Vh + vo + vLane1, &Vs[cur ^ 1][ldsW + 512]);
      }

      if (kbase <= q0 + 31) {  // causal work remains for this wave
        const unsigned short* Kc = Ks[cur];
        const unsigned short* Vc = Vs[cur];
        bf16x8 kf0[4], kf1[4];
#pragma unroll
        for (int c = 0; c < 4; ++c) {
          kf0[c] = *(const bf16x8*)&Kc[kfo0[c]];
          kf1[c] = *(const bf16x8*)&Kc[kfo1[c]];
        }
        bf16x8 vf[2][4];
#pragma unroll
        for (int kc = 0; kc < 2; ++kc)
#pragma unroll
          for (int d = 0; d < 4; ++d) vf[kc][d] = *(const bf16x8*)&Vc[vfo[kc][d]];

        // S^T = K . Q^T : D[row = k_local = c*16+lg*4+i, col = q = l15]
        floatx4 st_[2][4] = {};
        __builtin_amdgcn_s_setprio(1);
#pragma unroll
        for (int c = 0; c < 4; ++c) {
          st_[0][c] = __builtin_amdgcn_mfma_f32_16x16x32_bf16(kf0[c], qf[0][0], st_[0][c], 0, 0, 0);
          st_[0][c] = __builtin_amdgcn_mfma_f32_16x16x32_bf16(kf1[c], qf[0][1], st_[0][c], 0, 0, 0);
          st_[1][c] = __builtin_amdgcn_mfma_f32_16x16x32_bf16(kf0[c], qf[1][0], st_[1][c], 0, 0, 0);
          st_[1][c] = __builtin_amdgcn_mfma_f32_16x16x32_bf16(kf1[c], qf[1][1], st_[1][c], 0, 0, 0);
        }
        __builtin_amdgcn_s_setprio(0);

        if (kbase + 63 > q0) {  // causal mask: k_local > q - kbase
#pragma unroll
          for (int t = 0; t < 2; ++t) {
            const int thr = q0 + t * 16 + l15 - kbase;
#pragma unroll
            for (int c = 0; c < 4; ++c)
#pragma unroll
              for (int i = 0; i < 4; ++i)
                if (c * 16 + lg * 4 + i > thr) st_[t][c][i] = -1e30f;
          }
        }

        // in-lane stats (lane owns one q-row), defer-max THR=8
        float lmax[2];
        bool need = false;
#pragma unroll
        for (int t = 0; t < 2; ++t) {
          float v0 = fmaxf(fmaxf(st_[t][0][0], st_[t][0][1]),
                           fmaxf(st_[t][0][2], st_[t][0][3]));
          float v1 = fmaxf(fmaxf(st_[t][1][0], st_[t][1][1]),
                           fmaxf(st_[t][1][2], st_[t][1][3]));
          float v2 = fmaxf(fmaxf(st_[t][2][0], st_[t][2][1]),
                           fmaxf(st_[t][2][2], st_[t][2][3]));
          float v3 = fmaxf(fmaxf(st_[t][3][0], st_[t][3][1]),
                           fmaxf(st_[t][3][2], st_[t][3][3]));
          lmax[t] = fmaxf(fmaxf(v0, v1), fmaxf(v2, v3));
          need |= (lmax[t] > m_run[t] + 8.0f);
        }
        if (__any(need)) {
#pragma unroll
          for (int t = 0; t < 2; ++t) {
            float pm = lmax[t];
            pm = fmaxf(pm, __shfl_xor(pm, 16));
            pm = fmaxf(pm, __shfl_xor(pm, 32));
            float mnew = fmaxf(m_run[t], pm);
            float alpha = EXP2(m_run[t] - mnew);
            m_run[t] = mnew;
            l_part[t] *= alpha;
#pragma unroll
            for (int c = 0; c < 4; ++c) o[t][c] *= alpha;
          }
        }

#pragma unroll
        for (int t = 0; t < 2; ++t) {
          const int tb = (wid * 2 + t) * 1024;
          float sum = 0.f;
#pragma unroll
          for (int c = 0; c < 4; ++c) {
#pragma unroll
            for (int i = 0; i < 4; ++i) {
              st_[t][c][i] = EXP2(st_[t][c][i] - m_run[t]);
              sum += st_[t][c][i];
            }
            uint2 wv;
            wv.x = pk2(st_[t][c][0], st_[t][c][1]);
            wv.y = pk2(st_[t][c][2], st_[t][c][3]);
            *(uint2*)&Ps[tb + pwo[c]] = wv;  // ds_write_b64, swizzled
          }
          l_part[t] += sum;
        }

        // O^T += V^T . P^T
        __builtin_amdgcn_s_setprio(1);
#pragma unroll
        for (int t = 0; t < 2; ++t) {
          const int tb = (wid * 2 + t) * 1024;
          bf16x8 pb0 = *(const bf16x8*)&Ps[tb + pro0];
          bf16x8 pb1 = *(const bf16x8*)&Ps[tb + pro1];
#pragma unroll
          for (int dt = 0; dt < 4; ++dt) {
            o[t][dt] = __builtin_amdgcn_mfma_f32_16x16x32_bf16(vf[0][dt], pb0, o[t][dt], 0, 0, 0);
            o[t][dt] = __builtin_amdgcn_mfma_f32_16x16x32_bf16(vf[1][dt], pb1, o[t][dt], 0, 0, 0);
          }
        }
        __builtin_amdgcn_s_setprio(0);
      }
    }

    // epilogue: reduce 4 lg-lane l partials via 2 shuffles; write O
#pragma unroll
    for (int t = 0; t < 2; ++t) {
      float l = l_part[t];
      l += __shfl_xor(l, 16);
      l += __shfl_xor(l, 32);
      float inv = 1.0f / l;
      int q = q0 + t * 16 + l15;
      size_t base = ((size_t)(b * T_SEQ + q)) * D_MODEL + h * HEAD_DIM;
#pragma unroll
      for (int dt = 0; dt < 4; ++dt) {
        unsigned int u0 = pk2(o[t][dt][0] * inv, o[t][dt][1] * inv);
        unsigned int u1 = pk2(o[t][dt][2] * inv, o[t][dt][3] * inv);
        *(unsigned int*)&Ob[base + dt * 16 + lg * 4] = u0;
        *(unsigned int*)&Ob[base + dt * 16 + lg * 4 + 2] = u1;
      }
    }
  }
}

extern "C" void kernel_launch(void* const* d_in, const int* in_sizes, int n_in,
                              void* d_out, int out_size, void* d_ws,
                              size_t ws_size, hipStream_t stream) {
  const float* x = (const float*)d_in[0];
  const float* w_qkv = (const float*)d_in[1];
  const float* w_proj = (const float*)d_in[2];
  float* out = (float*)d_out;

  char* ws = (char*)d_ws;
  size_t off = 0;
  unsigned short* x_bf = (unsigned short*)(ws + off);
  off += (size_t)M_ROWS * D_MODEL * 2;
  unsigned short* wqkv_t = (unsigned short*)(ws + off);
  off += (size_t)D_MODEL * 3 * D_MODEL * 2;
  unsigned short* wproj_t = (unsigned short*)(ws + off);
  off += (size_t)D_MODEL * D_MODEL * 2;
  unsigned short* Qb = (unsigned short*)(ws + off);
  off += (size_t)BH_TOT * T_SEQ * HEAD_DIM * 2;
  unsigned short* Kb = (unsigned short*)(ws + off);
  off += (size_t)BH_TOT * T_SEQ * HEAD_DIM * 2;
  unsigned short* Vt = (unsigned short*)(ws + off);
  off += (size_t)BH_TOT * T_SEQ * HEAD_DIM * 2;
  unsigned short* Ob = (unsigned short*)(ws + off);
  off += (size_t)M_ROWS * D_MODEL * 2;

  int n1 = M_ROWS * D_MODEL;
  cvt_f32_bf16<<<(n1 / 4 + 255) / 256, 256, 0, stream>>>(x, x_bf, n1);
  cvt_transpose<<<dim3(3 * D_MODEL / 32, D_MODEL / 32), 256, 0, stream>>>(
      w_qkv, wqkv_t, D_MODEL, 3 * D_MODEL);
  cvt_transpose<<<dim3(D_MODEL / 32, D_MODEL / 32), 256, 0, stream>>>(
      w_proj, wproj_t, D_MODEL, D_MODEL);

  gemm_bf16<0><<<dim3(3 * D_MODEL / 128, M_ROWS / 128), 256, 0, stream>>>(
      x_bf, wqkv_t, M_ROWS, 3 * D_MODEL, D_MODEL, Qb, Kb, Vt, nullptr);

  attn_fwd<<<dim3(BH_TOT, 8), 256, 0, stream>>>(Qb, Kb, Vt, Ob);

  gemm_bf16<1><<<dim3(D_MODEL / 128, M_ROWS / 128), 256, 0, stream>>>(
      Ob, wproj_t, M_ROWS, D_MODEL, D_MODEL, nullptr, nullptr, nullptr, out);
}

// Round 12
// 187.491 us; speedup vs baseline: 2.9859x; 1.0579x over previous
//
#include <hip/hip_runtime.h>
#include <hip/hip_bf16.h>
#include <stdint.h>

#define D_MODEL 1024
#define N_HEADS 16
#define HEAD_DIM 64
#define B_SZ 4
#define T_SEQ 2048
#define BH_TOT (B_SZ * N_HEADS)     // 64
#define M_ROWS (B_SZ * T_SEQ)       // 8192

typedef float floatx4 __attribute__((ext_vector_type(4)));
typedef __bf16 bf16x8 __attribute__((ext_vector_type(8)));

#if __has_builtin(__builtin_amdgcn_exp2f)
#define EXP2(x) __builtin_amdgcn_exp2f(x)
#else
#define EXP2(x) exp2f(x)
#endif

__device__ inline unsigned short f2bf(float f) {
  union { float f; unsigned int u; } c; c.f = f;
  unsigned int u = c.u;
  unsigned int r = (u + 0x7FFFu + ((u >> 16) & 1u)) >> 16;
  return (unsigned short)r;
}

__device__ inline unsigned short bfc(float f) {  // native cvt (RNE)
  return __builtin_bit_cast(unsigned short, (__bf16)f);
}

__device__ inline unsigned int pk2(float lo, float hi) {  // 2xbf16 in u32
  return (unsigned int)bfc(lo) | ((unsigned int)bfc(hi) << 16);
}

__device__ __forceinline__ void gload16(const unsigned short* g,
                                        unsigned short* l) {
  __builtin_amdgcn_global_load_lds(
      (const __attribute__((address_space(1))) void*)g,
      (__attribute__((address_space(3))) void*)l, 16, 0, 0);
}

// ---------------- fp32 -> bf16 convert (no transpose) ----------------
__global__ void cvt_f32_bf16(const float* __restrict__ in,
                             unsigned short* __restrict__ out, int n) {
  int i = (blockIdx.x * blockDim.x + threadIdx.x) * 4;
  if (i + 3 < n) {
    float4 v = *(const float4*)(in + i);
    out[i + 0] = f2bf(v.x);
    out[i + 1] = f2bf(v.y);
    out[i + 2] = f2bf(v.z);
    out[i + 3] = f2bf(v.w);
  } else {
    for (; i < n; ++i) out[i] = f2bf(in[i]);
  }
}

// ---------------- fp32 [K][N] -> bf16 [N][K] transpose ----------------
__global__ __launch_bounds__(256) void cvt_transpose(
    const float* __restrict__ in, unsigned short* __restrict__ out,
    int K, int N) {
  __shared__ unsigned short tile[32][33];
  const int n0 = blockIdx.x * 32;
  const int k0 = blockIdx.y * 32;
  const int tx = threadIdx.x & 31;
  const int ty = threadIdx.x >> 5;  // 0..7
#pragma unroll
  for (int r = ty; r < 32; r += 8)
    tile[r][tx] = f2bf(in[(size_t)(k0 + r) * N + n0 + tx]);
  __syncthreads();
#pragma unroll
  for (int r = ty; r < 32; r += 8)
    out[(size_t)(n0 + r) * K + k0 + tx] = tile[tx][r];
}

// ---------------- bf16 MFMA GEMM, 128x128 tile, BK=64 ------------------
// global_load_lds staging with PRE-SWIZZLED source (slot^=row&7): linear
// LDS [128][64] u16, 128B rows = full bank wrap -> conflict-free b128
// fragment reads via the same XOR. 16 K-steps (half the barrier drains).
// EPI 0: qkv epilogue. Q scaled by 0.125*log2e -> Qb[bh][t][64];
//        K -> Kb[bh][t][64]; V written TRANSPOSED to Vt[bh][64][t].
#define QSCALE 0.1803368801111204f  // 0.125 * log2(e)
template <int EPI>
__global__ __launch_bounds__(256) void gemm_bf16(
    const unsigned short* __restrict__ A,
    const unsigned short* __restrict__ Bt, int M, int N, int K,
    unsigned short* __restrict__ Qb, unsigned short* __restrict__ Kb,
    unsigned short* __restrict__ Vt, float* __restrict__ Cout) {
  const int bn = blockIdx.x * 128;
  const int bm = blockIdx.y * 128;
  const int tid = threadIdx.x;
  const int lane = tid & 63;
  const int w = tid >> 6;
  const int wr = w >> 1, wc = w & 1;  // 2x2 waves, each 64x64
  const int l15 = lane & 15;
  const int lg = lane >> 4;
  const int l7 = l15 & 7;

  __shared__ unsigned short As[128 * 64];
  __shared__ unsigned short Bs[128 * 64];

  floatx4 acc[4][4] = {};

  const int srl = lane >> 3;                    // local staging row 0..7
  const int ssw = ((lane & 7) ^ srl) * 8;       // swizzled source col (u16)

  for (int k0 = 0; k0 < K; k0 += 64) {
#pragma unroll
    for (int p2 = 0; p2 < 4; ++p2) {
      const int rbase = p2 * 32 + w * 8;
      gload16(&A[(size_t)(bm + rbase + srl) * K + k0 + ssw], &As[rbase * 64]);
      gload16(&Bt[(size_t)(bn + rbase + srl) * K + k0 + ssw], &Bs[rbase * 64]);
    }
    __syncthreads();

#pragma unroll
    for (int kk = 0; kk < 2; ++kk) {
      bf16x8 af[4], bfr[4];
#pragma unroll
      for (int mt = 0; mt < 4; ++mt)
        af[mt] = *(const bf16x8*)&As[(wr * 64 + mt * 16 + l15) * 64 +
                                     (((kk * 4 + lg) ^ l7) << 3)];
#pragma unroll
      for (int nt = 0; nt < 4; ++nt)
        bfr[nt] = *(const bf16x8*)&Bs[(wc * 64 + nt * 16 + l15) * 64 +
                                      (((kk * 4 + lg) ^ l7) << 3)];
#pragma unroll
      for (int mt = 0; mt < 4; ++mt)
#pragma unroll
        for (int nt = 0; nt < 4; ++nt)
          acc[mt][nt] = __builtin_amdgcn_mfma_f32_16x16x32_bf16(
              af[mt], bfr[nt], acc[mt][nt], 0, 0, 0);
    }
    __syncthreads();
  }

#pragma unroll
  for (int mt = 0; mt < 4; ++mt)
#pragma unroll
    for (int nt = 0; nt < 4; ++nt) {
      const int n = bn + wc * 64 + nt * 16 + l15;
      const int m0 = bm + wr * 64 + mt * 16 + lg * 4;
      if (EPI == 0 && (n >> 10) == 2) {
        // V: write transposed, vectorized over the 4 consecutive t
        int b = m0 >> 11;
        int t = m0 & (T_SEQ - 1);
        int nn = n & (D_MODEL - 1);
        int h = nn >> 6;
        int dh = nn & 63;
        ushort4 v4;
        v4.x = bfc(acc[mt][nt][0]);
        v4.y = bfc(acc[mt][nt][1]);
        v4.z = bfc(acc[mt][nt][2]);
        v4.w = bfc(acc[mt][nt][3]);
        *(ushort4*)&Vt[((size_t)((b * N_HEADS + h) * HEAD_DIM) + dh) * T_SEQ +
                       t] = v4;
      } else {
#pragma unroll
        for (int i = 0; i < 4; ++i) {
          int m = m0 + i;
          float v = acc[mt][nt][i];
          if (EPI == 0) {
            int b = m >> 11;
            int t = m & (T_SEQ - 1);
            int part = n >> 10;  // 0=q 1=k
            int nn = n & (D_MODEL - 1);
            int h = nn >> 6;
            int dh = nn & 63;
            size_t idx =
                ((size_t)(b * N_HEADS + h) * T_SEQ + t) * HEAD_DIM + dh;
            if (part == 0)
              Qb[idx] = bfc(v * QSCALE);
            else
              Kb[idx] = bfc(v);
          } else {
            Cout[(size_t)m * N + n] = v;
          }
        }
      }
    }
}

// ---------------- causal flash attention, swapped-QK^T + gload_lds ------
// (unchanged from round 11 — 198us config)
__global__ __launch_bounds__(256) void attn_fwd(
    const unsigned short* __restrict__ Qb, const unsigned short* __restrict__ Kb,
    const unsigned short* __restrict__ Vt, unsigned short* __restrict__ Ob) {
  const int head = blockIdx.x;  // 0..63
  const int p = blockIdx.y;     // 0..7
  const int tid = threadIdx.x;
  const int wid = tid >> 6;
  const int lane = tid & 63;
  const int l15 = lane & 15;
  const int lg = lane >> 4;
  const int l7 = l15 & 7;
  const int b = head >> 4;
  const int h = head & 15;

  const unsigned short* Qh = Qb + (size_t)head * T_SEQ * HEAD_DIM;
  const unsigned short* Kh = Kb + (size_t)head * T_SEQ * HEAD_DIM;
  const unsigned short* Vh = Vt + (size_t)head * HEAD_DIM * T_SEQ;

  __shared__ unsigned short Ks[2][64 * 64];
  __shared__ unsigned short Vs[2][64 * 64];
  __shared__ unsigned short Ps[4 * 2 * 16 * 64];  // wave-private, swizzled

  const int swz8 = (((lane & 7) ^ (lane >> 3)) << 3);  // u16 units
  const int srow = wid * 16 + (lane >> 3);
  const size_t kLane0 = (size_t)srow * HEAD_DIM + swz8;
  const size_t kLane1 = (size_t)(srow + 8) * HEAD_DIM + swz8;
  const size_t vLane0 = (size_t)srow * T_SEQ + swz8;
  const size_t vLane1 = (size_t)(srow + 8) * T_SEQ + swz8;
  const int ldsW = wid * 1024;  // u16: wave's 2KB region per tile

  int kfo0[4], kfo1[4], vfo[2][4];
#pragma unroll
  for (int c = 0; c < 4; ++c) {
    kfo0[c] = (c * 16 + l15) * 64 + ((lg ^ l7) << 3);
    kfo1[c] = (c * 16 + l15) * 64 + (((4 + lg) ^ l7) << 3);
  }
#pragma unroll
  for (int kc = 0; kc < 2; ++kc)
#pragma unroll
    for (int d = 0; d < 4; ++d)
      vfo[kc][d] = (d * 16 + l15) * 64 + (((kc * 4 + lg) ^ l7) << 3);
  int pwo[4];
#pragma unroll
  for (int c = 0; c < 4; ++c)
    pwo[c] = l15 * 64 + (((2 * c + (lg >> 1)) ^ l7) << 3) + (lg & 1) * 4;
  const int pro0 = l15 * 64 + ((lg ^ l7) << 3);
  const int pro1 = l15 * 64 + (((4 + lg) ^ l7) << 3);

  for (int ph = 0; ph < 2; ++ph) {
    const int rbase = (ph == 0) ? p * 128 : 2048 - 128 * (p + 1);
    const int nst = (ph == 0) ? 2 * p + 2 : 32 - 2 * p;
    const int q0 = rbase + wid * 32;

    bf16x8 qf[2][2];
#pragma unroll
    for (int t = 0; t < 2; ++t)
#pragma unroll
      for (int c = 0; c < 2; ++c)
        qf[t][c] = *(const bf16x8*)&Qh[(size_t)(q0 + t * 16 + l15) * 64 +
                                       c * 32 + lg * 8];

    floatx4 o[2][4] = {};
    float m_run[2] = {-1e30f, -1e30f};
    float l_part[2] = {0.f, 0.f};

    __syncthreads();  // previous phase's reads fully done before restaging
    gload16(Kh + kLane0, &Ks[0][ldsW]);
    gload16(Kh + kLane1, &Ks[0][ldsW + 512]);
    gload16(Vh + vLane0, &Vs[0][ldsW]);
    gload16(Vh + vLane1, &Vs[0][ldsW + 512]);

    int cur = 0;
    for (int kb = 0; kb < nst; ++kb, cur ^= 1) {
      const int kbase = kb * 64;
      __syncthreads();  // drains vmcnt -> buf[cur] fully staged, all waves

      if (kb + 1 < nst) {  // issue next chunk into idle buffer (hidden)
        const size_t ko = (size_t)(kbase + 64) * HEAD_DIM;
        const int vo = kbase + 64;
        gload16(Kh + ko + kLane0, &Ks[cur ^ 1][ldsW]);
        gload16(Kh + ko + kLane1, &Ks[cur ^ 1][ldsW + 512]);
        gload16(Vh + vo + vLane0, &Vs[cur ^ 1][ldsW]);
        gload16(Vh + vo + vLane1, &Vs[cur ^ 1][ldsW + 512]);
      }

      if (kbase <= q0 + 31) {  // causal work remains for this wave
        const unsigned short* Kc = Ks[cur];
        const unsigned short* Vc = Vs[cur];
        bf16x8 kf0[4], kf1[4];
#pragma unroll
        for (int c = 0; c < 4; ++c) {
          kf0[c] = *(const bf16x8*)&Kc[kfo0[c]];
          kf1[c] = *(const bf16x8*)&Kc[kfo1[c]];
        }
        bf16x8 vf[2][4];
#pragma unroll
        for (int kc = 0; kc < 2; ++kc)
#pragma unroll
          for (int d = 0; d < 4; ++d) vf[kc][d] = *(const bf16x8*)&Vc[vfo[kc][d]];

        // S^T = K . Q^T : D[row = k_local = c*16+lg*4+i, col = q = l15]
        floatx4 st_[2][4] = {};
        __builtin_amdgcn_s_setprio(1);
#pragma unroll
        for (int c = 0; c < 4; ++c) {
          st_[0][c] = __builtin_amdgcn_mfma_f32_16x16x32_bf16(kf0[c], qf[0][0], st_[0][c], 0, 0, 0);
          st_[0][c] = __builtin_amdgcn_mfma_f32_16x16x32_bf16(kf1[c], qf[0][1], st_[0][c], 0, 0, 0);
          st_[1][c] = __builtin_amdgcn_mfma_f32_16x16x32_bf16(kf0[c], qf[1][0], st_[1][c], 0, 0, 0);
          st_[1][c] = __builtin_amdgcn_mfma_f32_16x16x32_bf16(kf1[c], qf[1][1], st_[1][c], 0, 0, 0);
        }
        __builtin_amdgcn_s_setprio(0);

        if (kbase + 63 > q0) {  // causal mask: k_local > q - kbase
#pragma unroll
          for (int t = 0; t < 2; ++t) {
            const int thr = q0 + t * 16 + l15 - kbase;
#pragma unroll
            for (int c = 0; c < 4; ++c)
#pragma unroll
              for (int i = 0; i < 4; ++i)
                if (c * 16 + lg * 4 + i > thr) st_[t][c][i] = -1e30f;
          }
        }

        float lmax[2];
        bool need = false;
#pragma unroll
        for (int t = 0; t < 2; ++t) {
          float v0 = fmaxf(fmaxf(st_[t][0][0], st_[t][0][1]),
                           fmaxf(st_[t][0][2], st_[t][0][3]));
          float v1 = fmaxf(fmaxf(st_[t][1][0], st_[t][1][1]),
                           fmaxf(st_[t][1][2], st_[t][1][3]));
          float v2 = fmaxf(fmaxf(st_[t][2][0], st_[t][2][1]),
                           fmaxf(st_[t][2][2], st_[t][2][3]));
          float v3 = fmaxf(fmaxf(st_[t][3][0], st_[t][3][1]),
                           fmaxf(st_[t][3][2], st_[t][3][3]));
          lmax[t] = fmaxf(fmaxf(v0, v1), fmaxf(v2, v3));
          need |= (lmax[t] > m_run[t] + 8.0f);
        }
        if (__any(need)) {
#pragma unroll
          for (int t = 0; t < 2; ++t) {
            float pm = lmax[t];
            pm = fmaxf(pm, __shfl_xor(pm, 16));
            pm = fmaxf(pm, __shfl_xor(pm, 32));
            float mnew = fmaxf(m_run[t], pm);
            float alpha = EXP2(m_run[t] - mnew);
            m_run[t] = mnew;
            l_part[t] *= alpha;
#pragma unroll
            for (int c = 0; c < 4; ++c) o[t][c] *= alpha;
          }
        }

#pragma unroll
        for (int t = 0; t < 2; ++t) {
          const int tb = (wid * 2 + t) * 1024;
          float sum = 0.f;
#pragma unroll
          for (int c = 0; c < 4; ++c) {
#pragma unroll
            for (int i = 0; i < 4; ++i) {
              st_[t][c][i] = EXP2(st_[t][c][i] - m_run[t]);
              sum += st_[t][c][i];
            }
            uint2 wv;
            wv.x = pk2(st_[t][c][0], st_[t][c][1]);
            wv.y = pk2(st_[t][c][2], st_[t][c][3]);
            *(uint2*)&Ps[tb + pwo[c]] = wv;  // ds_write_b64, swizzled
          }
          l_part[t] += sum;
        }

        // O^T += V^T . P^T
        __builtin_amdgcn_s_setprio(1);
#pragma unroll
        for (int t = 0; t < 2; ++t) {
          const int tb = (wid * 2 + t) * 1024;
          bf16x8 pb0 = *(const bf16x8*)&Ps[tb + pro0];
          bf16x8 pb1 = *(const bf16x8*)&Ps[tb + pro1];
#pragma unroll
          for (int dt = 0; dt < 4; ++dt) {
            o[t][dt] = __builtin_amdgcn_mfma_f32_16x16x32_bf16(vf[0][dt], pb0, o[t][dt], 0, 0, 0);
            o[t][dt] = __builtin_amdgcn_mfma_f32_16x16x32_bf16(vf[1][dt], pb1, o[t][dt], 0, 0, 0);
          }
        }
        __builtin_amdgcn_s_setprio(0);
      }
    }

    // epilogue: reduce 4 lg-lane l partials via 2 shuffles; write O
#pragma unroll
    for (int t = 0; t < 2; ++t) {
      float l = l_part[t];
      l += __shfl_xor(l, 16);
      l += __shfl_xor(l, 32);
      float inv = 1.0f / l;
      int q = q0 + t * 16 + l15;
      size_t base = ((size_t)(b * T_SEQ + q)) * D_MODEL + h * HEAD_DIM;
#pragma unroll
      for (int dt = 0; dt < 4; ++dt) {
        unsigned int u0 = pk2(o[t][dt][0] * inv, o[t][dt][1] * inv);
        unsigned int u1 = pk2(o[t][dt][2] * inv, o[t][dt][3] * inv);
        *(unsigned int*)&Ob[base + dt * 16 + lg * 4] = u0;
        *(unsigned int*)&Ob[base + dt * 16 + lg * 4 + 2] = u1;
      }
    }
  }
}

extern "C" void kernel_launch(void* const* d_in, const int* in_sizes, int n_in,
                              void* d_out, int out_size, void* d_ws,
                              size_t ws_size, hipStream_t stream) {
  const float* x = (const float*)d_in[0];
  const float* w_qkv = (const float*)d_in[1];
  const float* w_proj = (const float*)d_in[2];
  float* out = (float*)d_out;

  char* ws = (char*)d_ws;
  size_t off = 0;
  unsigned short* x_bf = (unsigned short*)(ws + off);
  off += (size_t)M_ROWS * D_MODEL * 2;
  unsigned short* wqkv_t = (unsigned short*)(ws + off);
  off += (size_t)D_MODEL * 3 * D_MODEL * 2;
  unsigned short* wproj_t = (unsigned short*)(ws + off);
  off += (size_t)D_MODEL * D_MODEL * 2;
  unsigned short* Qb = (unsigned short*)(ws + off);
  off += (size_t)BH_TOT * T_SEQ * HEAD_DIM * 2;
  unsigned short* Kb = (unsigned short*)(ws + off);
  off += (size_t)BH_TOT * T_SEQ * HEAD_DIM * 2;
  unsigned short* Vt = (unsigned short*)(ws + off);
  off += (size_t)BH_TOT * T_SEQ * HEAD_DIM * 2;
  unsigned short* Ob = (unsigned short*)(ws + off);
  off += (size_t)M_ROWS * D_MODEL * 2;

  int n1 = M_ROWS * D_MODEL;
  cvt_f32_bf16<<<(n1 / 4 + 255) / 256, 256, 0, stream>>>(x, x_bf, n1);
  cvt_transpose<<<dim3(3 * D_MODEL / 32, D_MODEL / 32), 256, 0, stream>>>(
      w_qkv, wqkv_t, D_MODEL, 3 * D_MODEL);
  cvt_transpose<<<dim3(D_MODEL / 32, D_MODEL / 32), 256, 0, stream>>>(
      w_proj, wproj_t, D_MODEL, D_MODEL);

  gemm_bf16<0><<<dim3(3 * D_MODEL / 128, M_ROWS / 128), 256, 0, stream>>>(
      x_bf, wqkv_t, M_ROWS, 3 * D_MODEL, D_MODEL, Qb, Kb, Vt, nullptr);

  attn_fwd<<<dim3(BH_TOT, 8), 256, 0, stream>>>(Qb, Kb, Vt, Ob);

  gemm_bf16<1><<<dim3(D_MODEL / 128, M_ROWS / 128), 256, 0, stream>>>(
      Ob, wproj_t, M_ROWS, D_MODEL, D_MODEL, nullptr, nullptr, nullptr, out);
}